// Round 4
// baseline (371.222 us; speedup 1.0000x reference)
//
#include <hip/hip_runtime.h>

#define NNODES 8192
#define KZ 20

// freqs[j] = 50^(-j/10)
static constexpr float FREQS[10] = {
  1.0f, 0.67624323f, 0.45730491f, 0.30924935f, 0.20912778f,
  0.14142136f, 0.09563524f, 0.06467268f, 0.04373443f, 0.02957512f};

// output offsets (floats)
#define O_XNE  0
#define O_POS  2621440
#define O_NBP  2646016
#define O_NBD  3137536
#define O_EDGE 6414336
#define O_FE   6578176

static __device__ __forceinline__ float bf2f(unsigned short h) {
  return __uint_as_float(((unsigned int)h) << 16);
}
static __device__ __forceinline__ unsigned short f2bf(float f) {
  unsigned int u = __float_as_uint(f);
  u += 0x7fffu + ((u >> 16) & 1u);
  return (unsigned short)(u >> 16);
}
static __device__ __forceinline__ unsigned long long umin64(unsigned long long a,
                                                           unsigned long long b) {
  return a < b ? a : b;
}

// ---------------- prep: positions, n2, ncac ----------------
__global__ __launch_bounds__(256) void k_prep(const float* __restrict__ affines,
                                              const int* __restrict__ prot_mask,
                                              const float* __restrict__ lit,
                                              float* __restrict__ out,
                                              float4* __restrict__ pos4,
                                              float4* __restrict__ ncac4) {
  int n = blockIdx.x * 256 + threadIdx.x;
  if (n >= NNODES) return;
  const float4* af = (const float4*)affines + (size_t)n * 3;
  float4 a0 = af[0], a1 = af[1], a2 = af[2];  // rows of rot, .w = trans
  float tx = a0.w, ty = a1.w, tz = a2.w;
  float n2;
  {
#pragma clang fp contract(off)
    // np: sum(pos*pos, -1) = ((x*x + y*y) + z*z), each op rounded, NO fma
    float xx = tx * tx;
    float yy = ty * ty;
    float zz = tz * tz;
    n2 = (xx + yy) + zz;
  }
  pos4[n] = make_float4(tx, ty, tz, n2);
  out[O_POS + n * 3 + 0] = tx;
  out[O_POS + n * 3 + 1] = ty;
  out[O_POS + n * 3 + 2] = tz;
  int aat = (prot_mask[n] != 0) ? 0 : 20;
  const float* lp = lit + aat * 9;
#pragma unroll
  for (int a = 0; a < 3; a++) {
    float l0 = lp[a * 3 + 0], l1 = lp[a * 3 + 1], l2 = lp[a * 3 + 2];
    // ncac[a][i] = sum_j rot[i][j] * lit[a][j] + trans[i]
    float x = a0.x * l0 + a0.y * l1 + a0.z * l2 + tx;
    float y = a1.x * l0 + a1.y * l1 + a1.z * l2 + ty;
    float z = a2.x * l0 + a2.y * l1 + a2.z * l2 + tz;
    ncac4[n * 3 + a] = make_float4(x, y, z, 0.f);
  }
}

// ---------------- fill x_ne: copy x, zero embedding cols ----------------
__global__ __launch_bounds__(256) void k_fill(const float4* __restrict__ x4,
                                              float4* __restrict__ out4) {
  int t = blockIdx.x * 256 + threadIdx.x;  // < 8192*80
  int n = t / 80, c = t % 80;
  out4[t] = (c < 64) ? x4[(size_t)n * 64 + c] : make_float4(0.f, 0.f, 0.f, 0.f);
}

// ---------------- transpose ne_weight -> Wt[2048][64] (zero pad) ----------------
__global__ __launch_bounds__(256) void k_wt(const float* __restrict__ w,
                                            float* __restrict__ wt) {
  int t = blockIdx.x * 256 + threadIdx.x;  // < 2048*64
  int k = t >> 6, o = t & 63;
  wt[t] = (k < 2000) ? w[(size_t)o * 2000 + k] : 0.f;
}

// ---------------- KNN: one block per query node ----------------
// d2 replicates np/BLAS f32 arithmetic bit-exactly:
//   dot = fmaf(z_i,z_j, fmaf(y_i,y_j, x_i*x_j))   (sgemm K-sequential FMA)
//   d2  = (n2_i + n2_j) - 2*dot                   (2*dot exact; one rounding)
// Ties (bit-equal d2) break to lower index, matching top_k.
__global__ __launch_bounds__(256) void k_knn(const float4* __restrict__ pos4,
                                             int* __restrict__ edge,
                                             float* __restrict__ out) {
  __shared__ unsigned int keys[NNODES];  // 32 KB
  __shared__ unsigned long long wmin[4];
  __shared__ unsigned long long res[KZ];
  int i = blockIdx.x;
  int tid = threadIdx.x;
  float4 pi = pos4[i];
  unsigned long long lmin = ~0ull;
  {
#pragma clang fp contract(off)
    for (int s = 0; s < 32; s++) {
      int c = s * 256 + tid;
      float4 pc = pos4[c];
      unsigned int key;
      if (c == i) {
        key = 0xFFFFFFFFu;  // above +inf's key; never selected
      } else {
        float dot = fmaf(pi.z, pc.z, fmaf(pi.y, pc.y, pi.x * pc.x));
        float s2 = pi.w + pc.w;
        float d2 = s2 - 2.0f * dot;
        unsigned int b = __float_as_uint(d2);
        key = (b & 0x80000000u) ? ~b : (b | 0x80000000u);  // order-preserving
      }
      keys[c] = key;
      unsigned long long packed = ((unsigned long long)key << 32) | (unsigned int)c;
      lmin = umin64(lmin, packed);
    }
  }
  __syncthreads();
  int lane = tid & 63, wid = tid >> 6;
  for (int k = 0; k < KZ; k++) {
    unsigned long long w = lmin;
#pragma unroll
    for (int off = 32; off > 0; off >>= 1)
      w = umin64(w, __shfl_xor(w, off, 64));
    if (lane == 0) wmin[wid] = w;
    __syncthreads();
    unsigned long long g =
        umin64(umin64(wmin[0], wmin[1]), umin64(wmin[2], wmin[3]));
    if (tid == 0) res[k] = g;
    if (lmin == g) {  // unique owner (index embedded in packed key)
      unsigned int c = (unsigned int)g;
      keys[c] = 0xFFFFFFFFu;
      unsigned long long nm = ~0ull;
      for (int s = 0; s < 32; s++) {
        int cc = s * 256 + tid;
        unsigned long long p =
            ((unsigned long long)keys[cc] << 32) | (unsigned int)cc;
        nm = umin64(nm, p);
      }
      lmin = nm;
    }
    __syncthreads();
  }
  if (tid < KZ) {
    int idx = (int)(res[tid] & 0xFFFFFFFFull);
    edge[(size_t)i * KZ + tid] = idx;
    float fi = (float)idx;
    out[O_EDGE + i * KZ + tid] = fi;                 // edge_index
    out[O_FE + i * KZ + tid] = fi;                   // full_edge row0
    out[O_FE + NNODES * KZ + i * KZ + tid] = (float)i;  // full_edge row1
  }
}

// ---------------- gather: nbp, nbd, enc (bf16) ----------------
__global__ __launch_bounds__(64) void k_gather(const float* __restrict__ affines,
                                               const float4* __restrict__ pos4,
                                               const float4* __restrict__ ncac4,
                                               const int* __restrict__ edge,
                                               float* __restrict__ out,
                                               unsigned short* __restrict__ enc) {
  __shared__ float distbuf[100];
  int i = blockIdx.x;
  int tid = threadIdx.x;
  if (tid < KZ) {
    const float4* af = (const float4*)affines + (size_t)i * 3;
    float4 a0 = af[0], a1 = af[1], a2 = af[2];
    float tx = a0.w, ty = a1.w, tz = a2.w;
    int idx = edge[(size_t)i * KZ + tid];
    float4 p = pos4[idx];
    float bx = p.x - tx, by = p.y - ty, bz = p.z - tz;
    // einsum('nji,nkj->nki'): v_i = sum_j rot[j][i] * b_j  (rot^T; rot NOT orthogonal)
    float vx = a0.x * bx + a1.x * by + a2.x * bz;
    float vy = a0.y * bx + a1.y * by + a2.y * bz;
    float vz = a0.z * bx + a1.z * by + a2.z * bz;
    out[O_NBP + i * 60 + tid * 3 + 0] = vx;
    out[O_NBP + i * 60 + tid * 3 + 1] = vy;
    out[O_NBP + i * 60 + tid * 3 + 2] = vz;
    float dn = sqrtf(vx * vx + vy * vy + vz * vz);
#pragma unroll
    for (int j = 0; j < 10; j++) {
      float a = dn * FREQS[j];
      out[O_NBD + i * 400 + tid * 20 + j] = __sinf(a);
      out[O_NBD + i * 400 + tid * 20 + 10 + j] = __cosf(a);
    }
    float4 cn = ncac4[(size_t)i * 3 + 0];   // n_pos
    float4 ca = ncac4[(size_t)i * 3 + 1];   // ca_pos
    float4 cc = ncac4[(size_t)i * 3 + 2];   // c_pos
    float4 nb0 = ncac4[(size_t)idx * 3 + 0];
    float4 nb1 = ncac4[(size_t)idx * 3 + 1];
    float4 nb2 = ncac4[(size_t)idx * 3 + 2];
    auto dist = [](float4 a, float4 b) {
      float dx = a.x - b.x, dy = a.y - b.y, dz = a.z - b.z;
      return sqrtf(dx * dx + dy * dy + dz * dz);
    };
    distbuf[tid * 3 + 0] = dist(nb0, ca);
    distbuf[tid * 3 + 1] = dist(nb1, ca);
    distbuf[tid * 3 + 2] = dist(nb2, ca);
    distbuf[60 + tid] = dist(nb2, cn);  // n_to_c
    distbuf[80 + tid] = dist(nb0, cc);  // c_to_n
  }
  __syncthreads();
  unsigned short* erow = enc + (size_t)i * 2048;
  for (int c = tid; c < 100; c += 64) {
    float d = distbuf[c];
    unsigned short sh[20];
#pragma unroll
    for (int j = 0; j < 10; j++) {
      float a = d * FREQS[j];
      sh[j] = f2bf(__sinf(a));
      sh[10 + j] = f2bf(__cosf(a));
    }
    unsigned int* dst = (unsigned int*)(erow + c * 20);
#pragma unroll
    for (int wq = 0; wq < 10; wq++)
      dst[wq] = (unsigned int)sh[2 * wq] | ((unsigned int)sh[2 * wq + 1] << 16);
  }
  if (tid >= 36 && tid < 60) {  // zero K-pad [2000,2048)
    unsigned int* dst = (unsigned int*)(erow + 2000 + (tid - 36) * 2);
    dst[0] = 0u;
  }
}

// ---------------- GEMM: (8192x2048 bf16) x (2048x64 f32) -> embedding ----------------
__global__ __launch_bounds__(256) void k_gemm(const unsigned short* __restrict__ enc,
                                              const float* __restrict__ wt,
                                              float* __restrict__ out) {
  __shared__ __align__(16) unsigned short a_lds[64 * 72];
  __shared__ __align__(16) float b_lds[64 * 68];
  int tid = threadIdx.x;
  int mt = blockIdx.x & 127;
  int ks = blockIdx.x >> 7;
  int n0 = mt * 64;
  int k0 = ks * 512;
  int ng = tid >> 4, og = tid & 15;
  float acc[4][4] = {};
  for (int ch = 0; ch < 8; ch++) {
    int kk = k0 + ch * 64;
    {  // stage A (64 rows x 64 k, bf16)
      int r = tid >> 3, seg = tid & 7;
#pragma unroll
      for (int p = 0; p < 2; p++) {
        int row = r + p * 32;
        const uint4* src =
            (const uint4*)(enc + (size_t)(n0 + row) * 2048 + kk + seg * 8);
        *(uint4*)&a_lds[row * 72 + seg * 8] = *src;
      }
    }
    {  // stage B (64 k x 64 o, f32)
      int rb = tid >> 2, sb = (tid & 3) * 16;
      const float4* src = (const float4*)(wt + (size_t)(kk + rb) * 64 + sb);
      float4* dst = (float4*)&b_lds[rb * 68 + sb];
#pragma unroll
      for (int q = 0; q < 4; q++) dst[q] = src[q];
    }
    __syncthreads();
#pragma unroll 4
    for (int j0 = 0; j0 < 64; j0 += 4) {
      float av[4][4];
#pragma unroll
      for (int nn = 0; nn < 4; nn++) {
        ushort4 t = *(const ushort4*)&a_lds[(ng * 4 + nn) * 72 + j0];
        av[nn][0] = bf2f(t.x); av[nn][1] = bf2f(t.y);
        av[nn][2] = bf2f(t.z); av[nn][3] = bf2f(t.w);
      }
      float4 b0 = *(const float4*)&b_lds[(j0 + 0) * 68 + og * 4];
      float4 b1 = *(const float4*)&b_lds[(j0 + 1) * 68 + og * 4];
      float4 b2 = *(const float4*)&b_lds[(j0 + 2) * 68 + og * 4];
      float4 b3 = *(const float4*)&b_lds[(j0 + 3) * 68 + og * 4];
#pragma unroll
      for (int nn = 0; nn < 4; nn++) {
        acc[nn][0] += av[nn][0]*b0.x + av[nn][1]*b1.x + av[nn][2]*b2.x + av[nn][3]*b3.x;
        acc[nn][1] += av[nn][0]*b0.y + av[nn][1]*b1.y + av[nn][2]*b2.y + av[nn][3]*b3.y;
        acc[nn][2] += av[nn][0]*b0.z + av[nn][1]*b1.z + av[nn][2]*b2.z + av[nn][3]*b3.z;
        acc[nn][3] += av[nn][0]*b0.w + av[nn][1]*b1.w + av[nn][2]*b2.w + av[nn][3]*b3.w;
      }
    }
    __syncthreads();
  }
#pragma unroll
  for (int nn = 0; nn < 4; nn++) {
    int row = n0 + ng * 4 + nn;
    float* base = out + (size_t)row * 320 + 256 + og * 4;
    atomicAdd(base + 0, acc[nn][0]);
    atomicAdd(base + 1, acc[nn][1]);
    atomicAdd(base + 2, acc[nn][2]);
    atomicAdd(base + 3, acc[nn][3]);
  }
}

extern "C" void kernel_launch(void* const* d_in, const int* in_sizes, int n_in,
                              void* d_out, int out_size, void* d_ws, size_t ws_size,
                              hipStream_t stream) {
  const float* x = (const float*)d_in[0];
  const float* affines = (const float*)d_in[1];
  const float* ne_w = (const float*)d_in[2];
  const float* lit = (const float*)d_in[3];
  const int* mask = (const int*)d_in[4];
  float* out = (float*)d_out;
  char* ws = (char*)d_ws;
  // ws layout (bytes)
  float4* pos4 = (float4*)(ws + 0);                   //  8192*16   = 131072
  float4* ncac4 = (float4*)(ws + 131072);             //  8192*48   -> 524288
  int* edge = (int*)(ws + 524288);                    //  8192*20*4 -> 1179648
  float* wt = (float*)(ws + 1179648);                 //  2048*64*4 -> 1703936
  unsigned short* enc = (unsigned short*)(ws + 1703936);  // 8192*2048*2 -> 35258368

  k_prep<<<32, 256, 0, stream>>>(affines, mask, lit, out, pos4, ncac4);
  k_fill<<<2560, 256, 0, stream>>>((const float4*)x, (float4*)out);
  k_wt<<<512, 256, 0, stream>>>(ne_w, wt);
  k_knn<<<8192, 256, 0, stream>>>(pos4, edge, out);
  k_gather<<<8192, 64, 0, stream>>>(affines, pos4, ncac4, edge, out, enc);
  k_gemm<<<512, 256, 0, stream>>>(enc, wt, out);
}

// Round 5
// 302.187 us; speedup vs baseline: 1.2285x; 1.2285x over previous
//
#include <hip/hip_runtime.h>

#define NNODES 8192
#define KZ 20

// freqs[j] = 50^(-j/10)
static constexpr float FREQS[10] = {
  1.0f, 0.67624323f, 0.45730491f, 0.30924935f, 0.20912778f,
  0.14142136f, 0.09563524f, 0.06467268f, 0.04373443f, 0.02957512f};

// output offsets (floats)
#define O_XNE  0
#define O_POS  2621440
#define O_NBP  2646016
#define O_NBD  3137536
#define O_EDGE 6414336
#define O_FE   6578176

static __device__ __forceinline__ float bf2f(unsigned short h) {
  return __uint_as_float(((unsigned int)h) << 16);
}
static __device__ __forceinline__ unsigned short f2bf(float f) {
  unsigned int u = __float_as_uint(f);
  u += 0x7fffu + ((u >> 16) & 1u);
  return (unsigned short)(u >> 16);
}

// ---------------- prep: positions, n2, ncac ----------------
__global__ __launch_bounds__(256) void k_prep(const float* __restrict__ affines,
                                              const int* __restrict__ prot_mask,
                                              const float* __restrict__ lit,
                                              float* __restrict__ out,
                                              float4* __restrict__ pos4,
                                              float4* __restrict__ ncac4) {
  int n = blockIdx.x * 256 + threadIdx.x;
  if (n >= NNODES) return;
  const float4* af = (const float4*)affines + (size_t)n * 3;
  float4 a0 = af[0], a1 = af[1], a2 = af[2];  // rows of rot, .w = trans
  float tx = a0.w, ty = a1.w, tz = a2.w;
  float n2;
  {
#pragma clang fp contract(off)
    // np: sum(pos*pos, -1) = ((x*x + y*y) + z*z), each op rounded, NO fma
    float xx = tx * tx;
    float yy = ty * ty;
    float zz = tz * tz;
    n2 = (xx + yy) + zz;
  }
  pos4[n] = make_float4(tx, ty, tz, n2);
  out[O_POS + n * 3 + 0] = tx;
  out[O_POS + n * 3 + 1] = ty;
  out[O_POS + n * 3 + 2] = tz;
  int aat = (prot_mask[n] != 0) ? 0 : 20;
  const float* lp = lit + aat * 9;
#pragma unroll
  for (int a = 0; a < 3; a++) {
    float l0 = lp[a * 3 + 0], l1 = lp[a * 3 + 1], l2 = lp[a * 3 + 2];
    // ncac[a][i] = sum_j rot[i][j] * lit[a][j] + trans[i]
    float x = a0.x * l0 + a0.y * l1 + a0.z * l2 + tx;
    float y = a1.x * l0 + a1.y * l1 + a1.z * l2 + ty;
    float z = a2.x * l0 + a2.y * l1 + a2.z * l2 + tz;
    ncac4[n * 3 + a] = make_float4(x, y, z, 0.f);
  }
}

// ---------------- fill x_ne: copy x, zero embedding cols ----------------
__global__ __launch_bounds__(256) void k_fill(const float4* __restrict__ x4,
                                              float4* __restrict__ out4) {
  int t = blockIdx.x * 256 + threadIdx.x;  // < 8192*80
  int n = t / 80, c = t % 80;
  out4[t] = (c < 64) ? x4[(size_t)n * 64 + c] : make_float4(0.f, 0.f, 0.f, 0.f);
}

// ---------------- transpose ne_weight -> Wt[2048][64] (zero pad) ----------------
__global__ __launch_bounds__(256) void k_wt(const float* __restrict__ w,
                                            float* __restrict__ wt) {
  int t = blockIdx.x * 256 + threadIdx.x;  // < 2048*64
  int k = t >> 6, o = t & 63;
  wt[t] = (k < 2000) ? w[(size_t)o * 2000 + k] : 0.f;
}

// ---------------- KNN: one block per query node ----------------
// d2 replicates np/BLAS f32 arithmetic bit-exactly:
//   dot = fmaf(z_i,z_j, fmaf(y_i,y_j, x_i*x_j)); d2 = (n2_i+n2_j) - 2*dot
// Selection: wave-partitioned. Each wave owns 2048 candidates, contiguous
// 32-candidate run per lane (so lowest-lane ballot == lowest index, and
// stable strict-< register top-3 keeps lowest s: exact top_k tie-break).
// 20 wave-internal min+ballot rounds (NO barriers), then one rank-select
// merge of the 4x20 (key,idx) u64 lists.
__global__ __launch_bounds__(256) void k_knn(const float4* __restrict__ pos4,
                                             int* __restrict__ edge,
                                             float* __restrict__ out) {
  __shared__ unsigned int keysp[9216];       // 8192 keys + 4-word pad per 32 (36 KB)
  __shared__ unsigned long long lists[80];   // 4 waves x 20 results
  int i = blockIdx.x;
  int tid = threadIdx.x;
  float4 pi = pos4[i];
  // ---- scan (coalesced), arithmetic identical to the passing version ----
  {
#pragma clang fp contract(off)
#pragma unroll 8
    for (int s = 0; s < 32; s++) {
      int c = s * 256 + tid;
      float4 pc = pos4[c];
      unsigned int key;
      if (c == i) {
        key = 0xFFFFFFFFu;  // self: never selected
      } else {
        float dot = fmaf(pi.z, pc.z, fmaf(pi.y, pc.y, pi.x * pc.x));
        float d2 = (pi.w + pc.w) - 2.0f * dot;
        unsigned int b = __float_as_uint(d2);
        key = (b & 0x80000000u) ? ~b : (b | 0x80000000u);  // order-preserving
      }
      keysp[c + ((c >> 5) << 2)] = key;
    }
  }
  __syncthreads();
  int lane = tid & 63, w = tid >> 6;
  int c0 = w * 2048 + lane * 32;        // my contiguous candidate run
  int a0 = c0 + ((c0 >> 5) << 2);       // padded word offset, 16B aligned
  unsigned int key[32];
#pragma unroll
  for (int q = 0; q < 8; q++) {
    uint4 v = *(const uint4*)&keysp[a0 + q * 4];
    key[q * 4 + 0] = v.x; key[q * 4 + 1] = v.y;
    key[q * 4 + 2] = v.z; key[q * 4 + 3] = v.w;
  }
  // ---- per-lane top-3 (stable: strict < keeps smallest s on ties) ----
  unsigned int m1 = 0xFFFFFFFFu, m2 = 0xFFFFFFFFu, m3 = 0xFFFFFFFFu;
  int p1 = 0, p2 = 0, p3 = 0;
#pragma unroll
  for (int s = 0; s < 32; s++) {
    unsigned int k = key[s];
    if (k < m1)      { m3 = m2; p3 = p2; m2 = m1; p2 = p1; m1 = k; p1 = s; }
    else if (k < m2) { m3 = m2; p3 = p2; m2 = k;  p2 = s; }
    else if (k < m3) { m3 = k;  p3 = s; }
  }
  unsigned int extracted = 0;  // bitmask over s of already-extracted candidates
  // ---- 20 extraction rounds, wave-local (no barriers) ----
  for (int k20 = 0; k20 < 20; k20++) {
    unsigned int m = m1;
#pragma unroll
    for (int off = 32; off; off >>= 1) {
      unsigned int o = (unsigned int)__shfl_xor((int)m, off, 64);
      m = (o < m) ? o : m;
    }
    unsigned long long vote = __ballot(m1 == m);
    int src = __ffsll((long long)vote) - 1;
    if (lane == src) {
      int c = c0 + p1;
      lists[w * 20 + k20] = ((unsigned long long)m << 13) | (unsigned int)c;
      extracted |= 1u << p1;
      m1 = m2; p1 = p2; m2 = m3; p2 = p3; m3 = 0xFFFFFFFFu;
      if (m1 == 0xFFFFFFFFu) {  // rare: rebuild top-3 from registers
        m2 = 0xFFFFFFFFu; m3 = 0xFFFFFFFFu;
#pragma unroll
        for (int s = 0; s < 32; s++) {
          unsigned int kk = ((extracted >> s) & 1u) ? 0xFFFFFFFFu : key[s];
          if (kk < m1)      { m3 = m2; p3 = p2; m2 = m1; p2 = p1; m1 = kk; p1 = s; }
          else if (kk < m2) { m3 = m2; p3 = p2; m2 = kk; p2 = s; }
          else if (kk < m3) { m3 = kk; p3 = s; }
        }
      }
    }
  }
  __syncthreads();
  // ---- merge 4x20 -> global top-20 by rank (u64 (key,idx): exact order) ----
  if (tid < 80) {
    unsigned long long my = lists[tid];
    int rank = 0;
    for (int t = 0; t < 80; t++) rank += (lists[t] < my) ? 1 : 0;
    if (rank < KZ) {
      int idx = (int)(my & 0x1FFFull);
      edge[(size_t)i * KZ + rank] = idx;
      float fi = (float)idx;
      out[O_EDGE + i * KZ + rank] = fi;                  // edge_index
      out[O_FE + i * KZ + rank] = fi;                    // full_edge row0
      out[O_FE + NNODES * KZ + i * KZ + rank] = (float)i;  // full_edge row1
    }
  }
}

// ---------------- gather: nbp, nbd, enc (bf16) ----------------
__global__ __launch_bounds__(64) void k_gather(const float* __restrict__ affines,
                                               const float4* __restrict__ pos4,
                                               const float4* __restrict__ ncac4,
                                               const int* __restrict__ edge,
                                               float* __restrict__ out,
                                               unsigned short* __restrict__ enc) {
  __shared__ float distbuf[100];
  int i = blockIdx.x;
  int tid = threadIdx.x;
  if (tid < KZ) {
    const float4* af = (const float4*)affines + (size_t)i * 3;
    float4 a0 = af[0], a1 = af[1], a2 = af[2];
    float tx = a0.w, ty = a1.w, tz = a2.w;
    int idx = edge[(size_t)i * KZ + tid];
    float4 p = pos4[idx];
    float bx = p.x - tx, by = p.y - ty, bz = p.z - tz;
    // einsum('nji,nkj->nki'): v_i = sum_j rot[j][i] * b_j  (rot^T; rot NOT orthogonal)
    float vx = a0.x * bx + a1.x * by + a2.x * bz;
    float vy = a0.y * bx + a1.y * by + a2.y * bz;
    float vz = a0.z * bx + a1.z * by + a2.z * bz;
    out[O_NBP + i * 60 + tid * 3 + 0] = vx;
    out[O_NBP + i * 60 + tid * 3 + 1] = vy;
    out[O_NBP + i * 60 + tid * 3 + 2] = vz;
    float dn = sqrtf(vx * vx + vy * vy + vz * vz);
#pragma unroll
    for (int j = 0; j < 10; j++) {
      float a = dn * FREQS[j];
      out[O_NBD + i * 400 + tid * 20 + j] = __sinf(a);
      out[O_NBD + i * 400 + tid * 20 + 10 + j] = __cosf(a);
    }
    float4 cn = ncac4[(size_t)i * 3 + 0];   // n_pos
    float4 ca = ncac4[(size_t)i * 3 + 1];   // ca_pos
    float4 cc = ncac4[(size_t)i * 3 + 2];   // c_pos
    float4 nb0 = ncac4[(size_t)idx * 3 + 0];
    float4 nb1 = ncac4[(size_t)idx * 3 + 1];
    float4 nb2 = ncac4[(size_t)idx * 3 + 2];
    auto dist = [](float4 a, float4 b) {
      float dx = a.x - b.x, dy = a.y - b.y, dz = a.z - b.z;
      return sqrtf(dx * dx + dy * dy + dz * dz);
    };
    distbuf[tid * 3 + 0] = dist(nb0, ca);
    distbuf[tid * 3 + 1] = dist(nb1, ca);
    distbuf[tid * 3 + 2] = dist(nb2, ca);
    distbuf[60 + tid] = dist(nb2, cn);  // n_to_c
    distbuf[80 + tid] = dist(nb0, cc);  // c_to_n
  }
  __syncthreads();
  unsigned short* erow = enc + (size_t)i * 2048;
  for (int c = tid; c < 100; c += 64) {
    float d = distbuf[c];
    unsigned short sh[20];
#pragma unroll
    for (int j = 0; j < 10; j++) {
      float a = d * FREQS[j];
      sh[j] = f2bf(__sinf(a));
      sh[10 + j] = f2bf(__cosf(a));
    }
    unsigned int* dst = (unsigned int*)(erow + c * 20);
#pragma unroll
    for (int wq = 0; wq < 10; wq++)
      dst[wq] = (unsigned int)sh[2 * wq] | ((unsigned int)sh[2 * wq + 1] << 16);
  }
  if (tid >= 36 && tid < 60) {  // zero K-pad [2000,2048)
    unsigned int* dst = (unsigned int*)(erow + 2000 + (tid - 36) * 2);
    dst[0] = 0u;
  }
}

// ---------------- GEMM: (8192x2048 bf16) x (2048x64 f32) -> embedding ----------------
__global__ __launch_bounds__(256) void k_gemm(const unsigned short* __restrict__ enc,
                                              const float* __restrict__ wt,
                                              float* __restrict__ out) {
  __shared__ __align__(16) unsigned short a_lds[64 * 72];
  __shared__ __align__(16) float b_lds[64 * 68];
  int tid = threadIdx.x;
  int mt = blockIdx.x & 127;
  int ks = blockIdx.x >> 7;
  int n0 = mt * 64;
  int k0 = ks * 512;
  int ng = tid >> 4, og = tid & 15;
  float acc[4][4] = {};
  for (int ch = 0; ch < 8; ch++) {
    int kk = k0 + ch * 64;
    {  // stage A (64 rows x 64 k, bf16)
      int r = tid >> 3, seg = tid & 7;
#pragma unroll
      for (int p = 0; p < 2; p++) {
        int row = r + p * 32;
        const uint4* src =
            (const uint4*)(enc + (size_t)(n0 + row) * 2048 + kk + seg * 8);
        *(uint4*)&a_lds[row * 72 + seg * 8] = *src;
      }
    }
    {  // stage B (64 k x 64 o, f32)
      int rb = tid >> 2, sb = (tid & 3) * 16;
      const float4* src = (const float4*)(wt + (size_t)(kk + rb) * 64 + sb);
      float4* dst = (float4*)&b_lds[rb * 68 + sb];
#pragma unroll
      for (int q = 0; q < 4; q++) dst[q] = src[q];
    }
    __syncthreads();
#pragma unroll 4
    for (int j0 = 0; j0 < 64; j0 += 4) {
      float av[4][4];
#pragma unroll
      for (int nn = 0; nn < 4; nn++) {
        ushort4 t = *(const ushort4*)&a_lds[(ng * 4 + nn) * 72 + j0];
        av[nn][0] = bf2f(t.x); av[nn][1] = bf2f(t.y);
        av[nn][2] = bf2f(t.z); av[nn][3] = bf2f(t.w);
      }
      float4 b0 = *(const float4*)&b_lds[(j0 + 0) * 68 + og * 4];
      float4 b1 = *(const float4*)&b_lds[(j0 + 1) * 68 + og * 4];
      float4 b2 = *(const float4*)&b_lds[(j0 + 2) * 68 + og * 4];
      float4 b3 = *(const float4*)&b_lds[(j0 + 3) * 68 + og * 4];
#pragma unroll
      for (int nn = 0; nn < 4; nn++) {
        acc[nn][0] += av[nn][0]*b0.x + av[nn][1]*b1.x + av[nn][2]*b2.x + av[nn][3]*b3.x;
        acc[nn][1] += av[nn][0]*b0.y + av[nn][1]*b1.y + av[nn][2]*b2.y + av[nn][3]*b3.y;
        acc[nn][2] += av[nn][0]*b0.z + av[nn][1]*b1.z + av[nn][2]*b2.z + av[nn][3]*b3.z;
        acc[nn][3] += av[nn][0]*b0.w + av[nn][1]*b1.w + av[nn][2]*b2.w + av[nn][3]*b3.w;
      }
    }
    __syncthreads();
  }
#pragma unroll
  for (int nn = 0; nn < 4; nn++) {
    int row = n0 + ng * 4 + nn;
    float* base = out + (size_t)row * 320 + 256 + og * 4;
    atomicAdd(base + 0, acc[nn][0]);
    atomicAdd(base + 1, acc[nn][1]);
    atomicAdd(base + 2, acc[nn][2]);
    atomicAdd(base + 3, acc[nn][3]);
  }
}

extern "C" void kernel_launch(void* const* d_in, const int* in_sizes, int n_in,
                              void* d_out, int out_size, void* d_ws, size_t ws_size,
                              hipStream_t stream) {
  const float* x = (const float*)d_in[0];
  const float* affines = (const float*)d_in[1];
  const float* ne_w = (const float*)d_in[2];
  const float* lit = (const float*)d_in[3];
  const int* mask = (const int*)d_in[4];
  float* out = (float*)d_out;
  char* ws = (char*)d_ws;
  // ws layout (bytes)
  float4* pos4 = (float4*)(ws + 0);                   //  8192*16   = 131072
  float4* ncac4 = (float4*)(ws + 131072);             //  8192*48   -> 524288
  int* edge = (int*)(ws + 524288);                    //  8192*20*4 -> 1179648
  float* wt = (float*)(ws + 1179648);                 //  2048*64*4 -> 1703936
  unsigned short* enc = (unsigned short*)(ws + 1703936);  // 8192*2048*2 -> 35258368

  k_prep<<<32, 256, 0, stream>>>(affines, mask, lit, out, pos4, ncac4);
  k_fill<<<2560, 256, 0, stream>>>((const float4*)x, (float4*)out);
  k_wt<<<512, 256, 0, stream>>>(ne_w, wt);
  k_knn<<<8192, 256, 0, stream>>>(pos4, edge, out);
  k_gather<<<8192, 64, 0, stream>>>(affines, pos4, ncac4, edge, out, enc);
  k_gemm<<<512, 256, 0, stream>>>(enc, wt, out);
}

// Round 6
// 246.698 us; speedup vs baseline: 1.5048x; 1.2249x over previous
//
#include <hip/hip_runtime.h>

#define NNODES 8192
#define KZ 20

// freqs[j] = 50^(-j/10)
static constexpr float FREQS[10] = {
  1.0f, 0.67624323f, 0.45730491f, 0.30924935f, 0.20912778f,
  0.14142136f, 0.09563524f, 0.06467268f, 0.04373443f, 0.02957512f};

// output offsets (floats)
#define O_XNE  0
#define O_POS  2621440
#define O_NBP  2646016
#define O_NBD  3137536
#define O_EDGE 6414336
#define O_FE   6578176

static __device__ __forceinline__ float bf2f(unsigned short h) {
  return __uint_as_float(((unsigned int)h) << 16);
}
static __device__ __forceinline__ unsigned short f2bf(float f) {
  unsigned int u = __float_as_uint(f);
  u += 0x7fffu + ((u >> 16) & 1u);
  return (unsigned short)(u >> 16);
}
static __device__ __forceinline__ unsigned int umin32(unsigned int a,
                                                      unsigned int b) {
  return a < b ? a : b;
}
// wave64 min-reduce via DPP (rocPRIM pattern): result valid in lane 63,
// broadcast via readlane. Pure VALU — no DS pipe, ~1-cyc ops.
static __device__ __forceinline__ unsigned int wave_min_u32(unsigned int v) {
  unsigned int t;
  t = (unsigned int)__builtin_amdgcn_update_dpp((int)v, (int)v, 0x111, 0xF, 0xF, false); v = umin32(v, t); // row_shr:1
  t = (unsigned int)__builtin_amdgcn_update_dpp((int)v, (int)v, 0x112, 0xF, 0xF, false); v = umin32(v, t); // row_shr:2
  t = (unsigned int)__builtin_amdgcn_update_dpp((int)v, (int)v, 0x114, 0xF, 0xF, false); v = umin32(v, t); // row_shr:4
  t = (unsigned int)__builtin_amdgcn_update_dpp((int)v, (int)v, 0x118, 0xF, 0xF, false); v = umin32(v, t); // row_shr:8
  t = (unsigned int)__builtin_amdgcn_update_dpp((int)v, (int)v, 0x142, 0xF, 0xF, false); v = umin32(v, t); // row_bcast:15
  t = (unsigned int)__builtin_amdgcn_update_dpp((int)v, (int)v, 0x143, 0xF, 0xF, false); v = umin32(v, t); // row_bcast:31
  return (unsigned int)__builtin_amdgcn_readlane((int)v, 63);
}

// ---------------- prep: positions, n2, ncac ----------------
__global__ __launch_bounds__(256) void k_prep(const float* __restrict__ affines,
                                              const int* __restrict__ prot_mask,
                                              const float* __restrict__ lit,
                                              float* __restrict__ out,
                                              float4* __restrict__ pos4,
                                              float4* __restrict__ ncac4) {
  int n = blockIdx.x * 256 + threadIdx.x;
  if (n >= NNODES) return;
  const float4* af = (const float4*)affines + (size_t)n * 3;
  float4 a0 = af[0], a1 = af[1], a2 = af[2];  // rows of rot, .w = trans
  float tx = a0.w, ty = a1.w, tz = a2.w;
  float n2;
  {
#pragma clang fp contract(off)
    // np: sum(pos*pos, -1) = ((x*x + y*y) + z*z), each op rounded, NO fma
    float xx = tx * tx;
    float yy = ty * ty;
    float zz = tz * tz;
    n2 = (xx + yy) + zz;
  }
  pos4[n] = make_float4(tx, ty, tz, n2);
  out[O_POS + n * 3 + 0] = tx;
  out[O_POS + n * 3 + 1] = ty;
  out[O_POS + n * 3 + 2] = tz;
  int aat = (prot_mask[n] != 0) ? 0 : 20;
  const float* lp = lit + aat * 9;
#pragma unroll
  for (int a = 0; a < 3; a++) {
    float l0 = lp[a * 3 + 0], l1 = lp[a * 3 + 1], l2 = lp[a * 3 + 2];
    // ncac[a][i] = sum_j rot[i][j] * lit[a][j] + trans[i]
    float x = a0.x * l0 + a0.y * l1 + a0.z * l2 + tx;
    float y = a1.x * l0 + a1.y * l1 + a1.z * l2 + ty;
    float z = a2.x * l0 + a2.y * l1 + a2.z * l2 + tz;
    ncac4[n * 3 + a] = make_float4(x, y, z, 0.f);
  }
}

// ---------------- fill x_ne: copy x, zero embedding cols ----------------
__global__ __launch_bounds__(256) void k_fill(const float4* __restrict__ x4,
                                              float4* __restrict__ out4) {
  int t = blockIdx.x * 256 + threadIdx.x;  // < 8192*80
  int n = t / 80, c = t % 80;
  out4[t] = (c < 64) ? x4[(size_t)n * 64 + c] : make_float4(0.f, 0.f, 0.f, 0.f);
}

// ---------------- transpose ne_weight -> Wt[2048][64] (zero pad) ----------------
__global__ __launch_bounds__(256) void k_wt(const float* __restrict__ w,
                                            float* __restrict__ wt) {
  int t = blockIdx.x * 256 + threadIdx.x;  // < 2048*64
  int k = t >> 6, o = t & 63;
  wt[t] = (k < 2000) ? w[(size_t)o * 2000 + k] : 0.f;
}

// ---------------- KNN: one block per query node ----------------
// d2 replicates np/BLAS f32 arithmetic bit-exactly:
//   dot = fmaf(z_i,z_j, fmaf(y_i,y_j, x_i*x_j)); d2 = (n2_i+n2_j) - 2*dot
// Thread tid owns candidates c = s*256+tid (strided; scan stays coalesced).
// All 32 keys live in VGPRs + inline register top-3 (stable: lowest s on
// ties). Per-wave: 20 DPP-min extraction rounds (no LDS, no barriers);
// exact cross-lane tie-break via second gated DPP reduce on (p1,lane)
// (lex == candidate-index order). Then rank-merge of 4x20 u64 lists.
__global__ __launch_bounds__(256) void k_knn(const float4* __restrict__ pos4,
                                             int* __restrict__ edge,
                                             float* __restrict__ out) {
  __shared__ unsigned long long lists[80];   // 4 waves x 20 results
  int i = blockIdx.x;
  int tid = threadIdx.x;
  float4 pi = pos4[i];
  unsigned int key[32];
  unsigned int m1 = 0xFFFFFFFFu, m2 = 0xFFFFFFFFu, m3 = 0xFFFFFFFFu;
  int p1 = 0, p2 = 0, p3 = 0;
  {
#pragma clang fp contract(off)
#pragma unroll
    for (int s = 0; s < 32; s++) {
      int c = s * 256 + tid;
      float4 pc = pos4[c];
      float dot = fmaf(pi.z, pc.z, fmaf(pi.y, pc.y, pi.x * pc.x));
      float d2 = (pi.w + pc.w) - 2.0f * dot;
      unsigned int b = __float_as_uint(d2);
      unsigned int k = (b & 0x80000000u) ? ~b : (b | 0x80000000u);  // monotone map
      if (c == i) k = 0xFFFFFFFFu;  // self: never selected
      key[s] = k;
      bool c1 = k < m1, c2 = k < m2, c3 = k < m3;  // c1 implies c2 implies c3
      m3 = c2 ? m2 : (c3 ? k : m3);  p3 = c2 ? p2 : (c3 ? s : p3);
      m2 = c1 ? m1 : (c2 ? k : m2);  p2 = c1 ? p1 : (c2 ? s : p2);
      m1 = c1 ? k : m1;              p1 = c1 ? s : p1;
    }
  }
  int lane = tid & 63, w = tid >> 6;
  unsigned int ext = 0;  // extracted-candidate bitmask over s
  for (int k20 = 0; k20 < 20; k20++) {
    unsigned int mk = wave_min_u32(m1);
    unsigned long long vote = __ballot(m1 == mk);
    int src;
    if (__popcll(vote) > 1) {
      // exact key tie across lanes: winner = lowest candidate index
      // c = p1*256 + w*64 + lane  ->  lex (p1, lane) within the wave
      unsigned int tb = (m1 == mk) ? (((unsigned int)p1 << 6) | (unsigned int)lane)
                                   : 0xFFFFFFFFu;
      src = (int)(wave_min_u32(tb) & 63u);
    } else {
      src = __ffsll((long long)vote) - 1;
    }
    if (lane == src) {
      int c = p1 * 256 + tid;
      lists[w * 20 + k20] = ((unsigned long long)mk << 13) | (unsigned int)c;
      ext |= 1u << p1;
      m1 = m2; p1 = p2; m2 = m3; p2 = p3; m3 = 0xFFFFFFFFu; p3 = 0;
      if (m1 == 0xFFFFFFFFu) {  // rare: rebuild top-3 from register keys
        m2 = 0xFFFFFFFFu; m3 = 0xFFFFFFFFu;
#pragma unroll
        for (int s = 0; s < 32; s++) {
          unsigned int kk = ((ext >> s) & 1u) ? 0xFFFFFFFFu : key[s];
          bool c1 = kk < m1, c2 = kk < m2, c3 = kk < m3;
          m3 = c2 ? m2 : (c3 ? kk : m3);  p3 = c2 ? p2 : (c3 ? s : p3);
          m2 = c1 ? m1 : (c2 ? kk : m2);  p2 = c1 ? p1 : (c2 ? s : p2);
          m1 = c1 ? kk : m1;              p1 = c1 ? s : p1;
        }
      }
    }
  }
  __syncthreads();
  // ---- merge 4x20 -> global top-20 by rank (u64 (key,idx): exact order) ----
  if (tid < 80) {
    unsigned long long my = lists[tid];
    int rank = 0;
    for (int t = 0; t < 80; t++) rank += (lists[t] < my) ? 1 : 0;
    if (rank < KZ) {
      int idx = (int)(my & 0x1FFFull);
      edge[(size_t)i * KZ + rank] = idx;
      float fi = (float)idx;
      out[O_EDGE + i * KZ + rank] = fi;                  // edge_index
      out[O_FE + i * KZ + rank] = fi;                    // full_edge row0
      out[O_FE + NNODES * KZ + i * KZ + rank] = (float)i;  // full_edge row1
    }
  }
}

// ---------------- gather: nbp, nbd, enc (bf16) ----------------
__global__ __launch_bounds__(64) void k_gather(const float* __restrict__ affines,
                                               const float4* __restrict__ pos4,
                                               const float4* __restrict__ ncac4,
                                               const int* __restrict__ edge,
                                               float* __restrict__ out,
                                               unsigned short* __restrict__ enc) {
  __shared__ float distbuf[100];
  int i = blockIdx.x;
  int tid = threadIdx.x;
  if (tid < KZ) {
    const float4* af = (const float4*)affines + (size_t)i * 3;
    float4 a0 = af[0], a1 = af[1], a2 = af[2];
    float tx = a0.w, ty = a1.w, tz = a2.w;
    int idx = edge[(size_t)i * KZ + tid];
    float4 p = pos4[idx];
    float bx = p.x - tx, by = p.y - ty, bz = p.z - tz;
    // einsum('nji,nkj->nki'): v_i = sum_j rot[j][i] * b_j  (rot^T; rot NOT orthogonal)
    float vx = a0.x * bx + a1.x * by + a2.x * bz;
    float vy = a0.y * bx + a1.y * by + a2.y * bz;
    float vz = a0.z * bx + a1.z * by + a2.z * bz;
    out[O_NBP + i * 60 + tid * 3 + 0] = vx;
    out[O_NBP + i * 60 + tid * 3 + 1] = vy;
    out[O_NBP + i * 60 + tid * 3 + 2] = vz;
    float dn = sqrtf(vx * vx + vy * vy + vz * vz);
#pragma unroll
    for (int j = 0; j < 10; j++) {
      float a = dn * FREQS[j];
      out[O_NBD + i * 400 + tid * 20 + j] = __sinf(a);
      out[O_NBD + i * 400 + tid * 20 + 10 + j] = __cosf(a);
    }
    float4 cn = ncac4[(size_t)i * 3 + 0];   // n_pos
    float4 ca = ncac4[(size_t)i * 3 + 1];   // ca_pos
    float4 cc = ncac4[(size_t)i * 3 + 2];   // c_pos
    float4 nb0 = ncac4[(size_t)idx * 3 + 0];
    float4 nb1 = ncac4[(size_t)idx * 3 + 1];
    float4 nb2 = ncac4[(size_t)idx * 3 + 2];
    auto dist = [](float4 a, float4 b) {
      float dx = a.x - b.x, dy = a.y - b.y, dz = a.z - b.z;
      return sqrtf(dx * dx + dy * dy + dz * dz);
    };
    distbuf[tid * 3 + 0] = dist(nb0, ca);
    distbuf[tid * 3 + 1] = dist(nb1, ca);
    distbuf[tid * 3 + 2] = dist(nb2, ca);
    distbuf[60 + tid] = dist(nb2, cn);  // n_to_c
    distbuf[80 + tid] = dist(nb0, cc);  // c_to_n
  }
  __syncthreads();
  unsigned short* erow = enc + (size_t)i * 2048;
  for (int c = tid; c < 100; c += 64) {
    float d = distbuf[c];
    unsigned short sh[20];
#pragma unroll
    for (int j = 0; j < 10; j++) {
      float a = d * FREQS[j];
      sh[j] = f2bf(__sinf(a));
      sh[10 + j] = f2bf(__cosf(a));
    }
    unsigned int* dst = (unsigned int*)(erow + c * 20);
#pragma unroll
    for (int wq = 0; wq < 10; wq++)
      dst[wq] = (unsigned int)sh[2 * wq] | ((unsigned int)sh[2 * wq + 1] << 16);
  }
  if (tid >= 36 && tid < 60) {  // zero K-pad [2000,2048)
    unsigned int* dst = (unsigned int*)(erow + 2000 + (tid - 36) * 2);
    dst[0] = 0u;
  }
}

// ---------------- GEMM: (8192x2048 bf16) x (2048x64 f32) -> embedding ----------------
__global__ __launch_bounds__(256) void k_gemm(const unsigned short* __restrict__ enc,
                                              const float* __restrict__ wt,
                                              float* __restrict__ out) {
  __shared__ __align__(16) unsigned short a_lds[64 * 72];
  __shared__ __align__(16) float b_lds[64 * 68];
  int tid = threadIdx.x;
  int mt = blockIdx.x & 127;
  int ks = blockIdx.x >> 7;
  int n0 = mt * 64;
  int k0 = ks * 512;
  int ng = tid >> 4, og = tid & 15;
  float acc[4][4] = {};
  for (int ch = 0; ch < 8; ch++) {
    int kk = k0 + ch * 64;
    {  // stage A (64 rows x 64 k, bf16)
      int r = tid >> 3, seg = tid & 7;
#pragma unroll
      for (int p = 0; p < 2; p++) {
        int row = r + p * 32;
        const uint4* src =
            (const uint4*)(enc + (size_t)(n0 + row) * 2048 + kk + seg * 8);
        *(uint4*)&a_lds[row * 72 + seg * 8] = *src;
      }
    }
    {  // stage B (64 k x 64 o, f32)
      int rb = tid >> 2, sb = (tid & 3) * 16;
      const float4* src = (const float4*)(wt + (size_t)(kk + rb) * 64 + sb);
      float4* dst = (float4*)&b_lds[rb * 68 + sb];
#pragma unroll
      for (int q = 0; q < 4; q++) dst[q] = src[q];
    }
    __syncthreads();
#pragma unroll 4
    for (int j0 = 0; j0 < 64; j0 += 4) {
      float av[4][4];
#pragma unroll
      for (int nn = 0; nn < 4; nn++) {
        ushort4 t = *(const ushort4*)&a_lds[(ng * 4 + nn) * 72 + j0];
        av[nn][0] = bf2f(t.x); av[nn][1] = bf2f(t.y);
        av[nn][2] = bf2f(t.z); av[nn][3] = bf2f(t.w);
      }
      float4 b0 = *(const float4*)&b_lds[(j0 + 0) * 68 + og * 4];
      float4 b1 = *(const float4*)&b_lds[(j0 + 1) * 68 + og * 4];
      float4 b2 = *(const float4*)&b_lds[(j0 + 2) * 68 + og * 4];
      float4 b3 = *(const float4*)&b_lds[(j0 + 3) * 68 + og * 4];
#pragma unroll
      for (int nn = 0; nn < 4; nn++) {
        acc[nn][0] += av[nn][0]*b0.x + av[nn][1]*b1.x + av[nn][2]*b2.x + av[nn][3]*b3.x;
        acc[nn][1] += av[nn][0]*b0.y + av[nn][1]*b1.y + av[nn][2]*b2.y + av[nn][3]*b3.y;
        acc[nn][2] += av[nn][0]*b0.z + av[nn][1]*b1.z + av[nn][2]*b2.z + av[nn][3]*b3.z;
        acc[nn][3] += av[nn][0]*b0.w + av[nn][1]*b1.w + av[nn][2]*b2.w + av[nn][3]*b3.w;
      }
    }
    __syncthreads();
  }
#pragma unroll
  for (int nn = 0; nn < 4; nn++) {
    int row = n0 + ng * 4 + nn;
    float* base = out + (size_t)row * 320 + 256 + og * 4;
    atomicAdd(base + 0, acc[nn][0]);
    atomicAdd(base + 1, acc[nn][1]);
    atomicAdd(base + 2, acc[nn][2]);
    atomicAdd(base + 3, acc[nn][3]);
  }
}

extern "C" void kernel_launch(void* const* d_in, const int* in_sizes, int n_in,
                              void* d_out, int out_size, void* d_ws, size_t ws_size,
                              hipStream_t stream) {
  const float* x = (const float*)d_in[0];
  const float* affines = (const float*)d_in[1];
  const float* ne_w = (const float*)d_in[2];
  const float* lit = (const float*)d_in[3];
  const int* mask = (const int*)d_in[4];
  float* out = (float*)d_out;
  char* ws = (char*)d_ws;
  // ws layout (bytes)
  float4* pos4 = (float4*)(ws + 0);                   //  8192*16   = 131072
  float4* ncac4 = (float4*)(ws + 131072);             //  8192*48   -> 524288
  int* edge = (int*)(ws + 524288);                    //  8192*20*4 -> 1179648
  float* wt = (float*)(ws + 1179648);                 //  2048*64*4 -> 1703936
  unsigned short* enc = (unsigned short*)(ws + 1703936);  // 8192*2048*2 -> 35258368

  k_prep<<<32, 256, 0, stream>>>(affines, mask, lit, out, pos4, ncac4);
  k_fill<<<2560, 256, 0, stream>>>((const float4*)x, (float4*)out);
  k_wt<<<512, 256, 0, stream>>>(ne_w, wt);
  k_knn<<<8192, 256, 0, stream>>>(pos4, edge, out);
  k_gather<<<8192, 64, 0, stream>>>(affines, pos4, ncac4, edge, out, enc);
  k_gemm<<<512, 256, 0, stream>>>(enc, wt, out);
}

// Round 7
// 243.021 us; speedup vs baseline: 1.5275x; 1.0151x over previous
//
#include <hip/hip_runtime.h>

#define NNODES 8192
#define KZ 20

// freqs[j] = 50^(-j/10)
static constexpr float FREQS[10] = {
  1.0f, 0.67624323f, 0.45730491f, 0.30924935f, 0.20912778f,
  0.14142136f, 0.09563524f, 0.06467268f, 0.04373443f, 0.02957512f};

// output offsets (floats)
#define O_XNE  0
#define O_POS  2621440
#define O_NBP  2646016
#define O_NBD  3137536
#define O_EDGE 6414336
#define O_FE   6578176

static __device__ __forceinline__ float bf2f(unsigned short h) {
  return __uint_as_float(((unsigned int)h) << 16);
}
static __device__ __forceinline__ unsigned short f2bf(float f) {
  unsigned int u = __float_as_uint(f);
  u += 0x7fffu + ((u >> 16) & 1u);
  return (unsigned short)(u >> 16);
}
static __device__ __forceinline__ unsigned int umin32(unsigned int a,
                                                      unsigned int b) {
  return a < b ? a : b;
}
// wave64 min-reduce via DPP: pure VALU, result broadcast via readlane(63).
static __device__ __forceinline__ unsigned int wave_min_u32(unsigned int v) {
  unsigned int t;
  t = (unsigned int)__builtin_amdgcn_update_dpp((int)v, (int)v, 0x111, 0xF, 0xF, false); v = umin32(v, t); // row_shr:1
  t = (unsigned int)__builtin_amdgcn_update_dpp((int)v, (int)v, 0x112, 0xF, 0xF, false); v = umin32(v, t); // row_shr:2
  t = (unsigned int)__builtin_amdgcn_update_dpp((int)v, (int)v, 0x114, 0xF, 0xF, false); v = umin32(v, t); // row_shr:4
  t = (unsigned int)__builtin_amdgcn_update_dpp((int)v, (int)v, 0x118, 0xF, 0xF, false); v = umin32(v, t); // row_shr:8
  t = (unsigned int)__builtin_amdgcn_update_dpp((int)v, (int)v, 0x142, 0xF, 0xF, false); v = umin32(v, t); // row_bcast:15
  t = (unsigned int)__builtin_amdgcn_update_dpp((int)v, (int)v, 0x143, 0xF, 0xF, false); v = umin32(v, t); // row_bcast:31
  return (unsigned int)__builtin_amdgcn_readlane((int)v, 63);
}

// ---------------- fused prep + x_ne fill + Wt transpose ----------------
__global__ __launch_bounds__(256) void k_pre(const float4* __restrict__ x4,
                                             const float* __restrict__ affines,
                                             const int* __restrict__ prot_mask,
                                             const float* __restrict__ lit,
                                             const float* __restrict__ w,
                                             float* __restrict__ out,
                                             float4* __restrict__ pos4,
                                             float4* __restrict__ ncac4,
                                             float* __restrict__ wt) {
  int t = blockIdx.x * 256 + threadIdx.x;  // < 655360
  {  // fill x_ne: copy x, zero embedding cols (float4 granularity)
    int n = t / 80, c = t % 80;
    ((float4*)out)[t] =
        (c < 64) ? x4[(size_t)n * 64 + c] : make_float4(0.f, 0.f, 0.f, 0.f);
  }
  if (t < NNODES) {  // prep: positions, n2, ncac
    int n = t;
    const float4* af = (const float4*)affines + (size_t)n * 3;
    float4 a0 = af[0], a1 = af[1], a2 = af[2];  // rows of rot, .w = trans
    float tx = a0.w, ty = a1.w, tz = a2.w;
    float n2;
    {
#pragma clang fp contract(off)
      // np: sum(pos*pos,-1) = ((x*x + y*y) + z*z), each op rounded, NO fma
      float xx = tx * tx;
      float yy = ty * ty;
      float zz = tz * tz;
      n2 = (xx + yy) + zz;
    }
    pos4[n] = make_float4(tx, ty, tz, n2);
    out[O_POS + n * 3 + 0] = tx;
    out[O_POS + n * 3 + 1] = ty;
    out[O_POS + n * 3 + 2] = tz;
    int aat = (prot_mask[n] != 0) ? 0 : 20;
    const float* lp = lit + aat * 9;
#pragma unroll
    for (int a = 0; a < 3; a++) {
      float l0 = lp[a * 3 + 0], l1 = lp[a * 3 + 1], l2 = lp[a * 3 + 2];
      // ncac[a][i] = sum_j rot[i][j]*lit[a][j] + trans[i]
      float x = a0.x * l0 + a0.y * l1 + a0.z * l2 + tx;
      float y = a1.x * l0 + a1.y * l1 + a1.z * l2 + ty;
      float z = a2.x * l0 + a2.y * l1 + a2.z * l2 + tz;
      ncac4[n * 3 + a] = make_float4(x, y, z, 0.f);
    }
  }
  if (t >= 524288) {  // Wt transpose: 131072 threads
    int u = t - 524288;
    int k = u >> 6, o = u & 63;
    wt[u] = (k < 2000) ? w[(size_t)o * 2000 + k] : 0.f;
  }
}

// ---------------- fused KNN + gather ----------------
// d2 replicates np/BLAS f32 arithmetic bit-exactly:
//   dot = fmaf(z_i,z_j, fmaf(y_i,y_j, x_i*x_j)); d2 = (n2_i+n2_j) - 2*dot
// Thread tid owns candidates c = s*256+tid (strided; scan stays coalesced).
// All 32 keys live in VGPRs + inline register top-3 (stable: lowest s on
// ties). 20 DPP-min extraction rounds per wave (no LDS/barriers); exact
// cross-lane tie-break via second gated DPP reduce on (p1,lane). Then
// rank-merge of 4x20 u64 lists, then gather/encode tail on same block.
__global__ __launch_bounds__(256) void k_knng(const float4* __restrict__ pos4,
                                              const float* __restrict__ affines,
                                              const float4* __restrict__ ncac4,
                                              float* __restrict__ out,
                                              unsigned short* __restrict__ enc) {
  __shared__ unsigned long long lists[80];   // 4 waves x 20 results
  __shared__ int nidx[KZ];                   // sorted neighbor indices
  __shared__ float distbuf[100];
  int i = blockIdx.x;
  int tid = threadIdx.x;
  float4 pi = pos4[i];
  unsigned int key[32];
  unsigned int m1 = 0xFFFFFFFFu, m2 = 0xFFFFFFFFu, m3 = 0xFFFFFFFFu;
  int p1 = 0, p2 = 0, p3 = 0;
  {
#pragma clang fp contract(off)
#pragma unroll
    for (int s = 0; s < 32; s++) {
      int c = s * 256 + tid;
      float4 pc = pos4[c];
      float dot = fmaf(pi.z, pc.z, fmaf(pi.y, pc.y, pi.x * pc.x));
      float d2 = (pi.w + pc.w) - 2.0f * dot;
      unsigned int b = __float_as_uint(d2);
      unsigned int k = (b & 0x80000000u) ? ~b : (b | 0x80000000u);  // monotone map
      if (c == i) k = 0xFFFFFFFFu;  // self: never selected
      key[s] = k;
      bool c1 = k < m1, c2 = k < m2, c3 = k < m3;  // c1 implies c2 implies c3
      m3 = c2 ? m2 : (c3 ? k : m3);  p3 = c2 ? p2 : (c3 ? s : p3);
      m2 = c1 ? m1 : (c2 ? k : m2);  p2 = c1 ? p1 : (c2 ? s : p2);
      m1 = c1 ? k : m1;              p1 = c1 ? s : p1;
    }
  }
  int lane = tid & 63, w = tid >> 6;
  unsigned int ext = 0;  // extracted-candidate bitmask over s
  for (int k20 = 0; k20 < 20; k20++) {
    unsigned int mk = wave_min_u32(m1);
    unsigned long long vote = __ballot(m1 == mk);
    int src;
    if (__popcll(vote) > 1) {
      // exact key tie across lanes: winner = lowest candidate index
      // c = p1*256 + w*64 + lane  ->  lex (p1, lane) within the wave
      unsigned int tb = (m1 == mk) ? (((unsigned int)p1 << 6) | (unsigned int)lane)
                                   : 0xFFFFFFFFu;
      src = (int)(wave_min_u32(tb) & 63u);
    } else {
      src = __ffsll((long long)vote) - 1;
    }
    if (lane == src) {
      int c = p1 * 256 + tid;
      lists[w * 20 + k20] = ((unsigned long long)mk << 13) | (unsigned int)c;
      ext |= 1u << p1;
      m1 = m2; p1 = p2; m2 = m3; p2 = p3; m3 = 0xFFFFFFFFu; p3 = 0;
      if (m1 == 0xFFFFFFFFu) {  // rare: rebuild top-3 from register keys
        m2 = 0xFFFFFFFFu; m3 = 0xFFFFFFFFu;
#pragma unroll
        for (int s = 0; s < 32; s++) {
          unsigned int kk = ((ext >> s) & 1u) ? 0xFFFFFFFFu : key[s];
          bool c1 = kk < m1, c2 = kk < m2, c3 = kk < m3;
          m3 = c2 ? m2 : (c3 ? kk : m3);  p3 = c2 ? p2 : (c3 ? s : p3);
          m2 = c1 ? m1 : (c2 ? kk : m2);  p2 = c1 ? p1 : (c2 ? s : p2);
          m1 = c1 ? kk : m1;              p1 = c1 ? s : p1;
        }
      }
    }
  }
  __syncthreads();
  // ---- merge 4x20 -> global top-20 by rank (u64 (key,idx): exact order) ----
  if (tid < 80) {
    unsigned long long my = lists[tid];
    int rank = 0;
    for (int t = 0; t < 80; t++) rank += (lists[t] < my) ? 1 : 0;
    if (rank < KZ) {
      int idx = (int)(my & 0x1FFFull);
      nidx[rank] = idx;
      float fi = (float)idx;
      out[O_EDGE + i * KZ + rank] = fi;                  // edge_index
      out[O_FE + i * KZ + rank] = fi;                    // full_edge row0
      out[O_FE + NNODES * KZ + i * KZ + rank] = (float)i;  // full_edge row1
    }
  }
  __syncthreads();
  // ---- gather tail: nbp, nbd, backbone distances ----
  if (tid < KZ) {
    const float4* af = (const float4*)affines + (size_t)i * 3;
    float4 a0 = af[0], a1 = af[1], a2 = af[2];
    float tx = a0.w, ty = a1.w, tz = a2.w;
    int idx = nidx[tid];
    float4 p = pos4[idx];
    float bx = p.x - tx, by = p.y - ty, bz = p.z - tz;
    // einsum('nji,nkj->nki'): v_i = sum_j rot[j][i]*b_j (rot^T; NOT orthogonal)
    float vx = a0.x * bx + a1.x * by + a2.x * bz;
    float vy = a0.y * bx + a1.y * by + a2.y * bz;
    float vz = a0.z * bx + a1.z * by + a2.z * bz;
    out[O_NBP + i * 60 + tid * 3 + 0] = vx;
    out[O_NBP + i * 60 + tid * 3 + 1] = vy;
    out[O_NBP + i * 60 + tid * 3 + 2] = vz;
    float dn = sqrtf(vx * vx + vy * vy + vz * vz);
#pragma unroll
    for (int j = 0; j < 10; j++) {
      float a = dn * FREQS[j];
      out[O_NBD + i * 400 + tid * 20 + j] = __sinf(a);
      out[O_NBD + i * 400 + tid * 20 + 10 + j] = __cosf(a);
    }
    float4 cn = ncac4[(size_t)i * 3 + 0];   // n_pos
    float4 ca = ncac4[(size_t)i * 3 + 1];   // ca_pos
    float4 cc = ncac4[(size_t)i * 3 + 2];   // c_pos
    float4 nb0 = ncac4[(size_t)idx * 3 + 0];
    float4 nb1 = ncac4[(size_t)idx * 3 + 1];
    float4 nb2 = ncac4[(size_t)idx * 3 + 2];
    auto dist = [](float4 a, float4 b) {
      float dx = a.x - b.x, dy = a.y - b.y, dz = a.z - b.z;
      return sqrtf(dx * dx + dy * dy + dz * dz);
    };
    distbuf[tid * 3 + 0] = dist(nb0, ca);
    distbuf[tid * 3 + 1] = dist(nb1, ca);
    distbuf[tid * 3 + 2] = dist(nb2, ca);
    distbuf[60 + tid] = dist(nb2, cn);  // n_to_c
    distbuf[80 + tid] = dist(nb0, cc);  // c_to_n
  }
  __syncthreads();
  // ---- enc encode (bf16), 100 cols over 256 threads ----
  unsigned short* erow = enc + (size_t)i * 2048;
  if (tid < 100) {
    float d = distbuf[tid];
    unsigned short sh[20];
#pragma unroll
    for (int j = 0; j < 10; j++) {
      float a = d * FREQS[j];
      sh[j] = f2bf(__sinf(a));
      sh[10 + j] = f2bf(__cosf(a));
    }
    unsigned int* dst = (unsigned int*)(erow + tid * 20);
#pragma unroll
    for (int wq = 0; wq < 10; wq++)
      dst[wq] = (unsigned int)sh[2 * wq] | ((unsigned int)sh[2 * wq + 1] << 16);
  } else if (tid >= 100 && tid < 124) {  // zero K-pad [2000,2048)
    unsigned int* dst = (unsigned int*)(erow + 2000 + (tid - 100) * 2);
    dst[0] = 0u;
  }
}

// ---------------- GEMM: (8192x2048 bf16) x (2048x64 f32) -> embedding ----------------
__global__ __launch_bounds__(256) void k_gemm(const unsigned short* __restrict__ enc,
                                              const float* __restrict__ wt,
                                              float* __restrict__ out) {
  __shared__ __align__(16) unsigned short a_lds[64 * 72];
  __shared__ __align__(16) float b_lds[64 * 68];
  int tid = threadIdx.x;
  int mt = blockIdx.x & 127;
  int ks = blockIdx.x >> 7;
  int n0 = mt * 64;
  int k0 = ks * 512;
  int ng = tid >> 4, og = tid & 15;
  float acc[4][4] = {};
  for (int ch = 0; ch < 8; ch++) {
    int kk = k0 + ch * 64;
    {  // stage A (64 rows x 64 k, bf16)
      int r = tid >> 3, seg = tid & 7;
#pragma unroll
      for (int p = 0; p < 2; p++) {
        int row = r + p * 32;
        const uint4* src =
            (const uint4*)(enc + (size_t)(n0 + row) * 2048 + kk + seg * 8);
        *(uint4*)&a_lds[row * 72 + seg * 8] = *src;
      }
    }
    {  // stage B (64 k x 64 o, f32)
      int rb = tid >> 2, sb = (tid & 3) * 16;
      const float4* src = (const float4*)(wt + (size_t)(kk + rb) * 64 + sb);
      float4* dst = (float4*)&b_lds[rb * 68 + sb];
#pragma unroll
      for (int q = 0; q < 4; q++) dst[q] = src[q];
    }
    __syncthreads();
#pragma unroll 4
    for (int j0 = 0; j0 < 64; j0 += 4) {
      float av[4][4];
#pragma unroll
      for (int nn = 0; nn < 4; nn++) {
        ushort4 t = *(const ushort4*)&a_lds[(ng * 4 + nn) * 72 + j0];
        av[nn][0] = bf2f(t.x); av[nn][1] = bf2f(t.y);
        av[nn][2] = bf2f(t.z); av[nn][3] = bf2f(t.w);
      }
      float4 b0 = *(const float4*)&b_lds[(j0 + 0) * 68 + og * 4];
      float4 b1 = *(const float4*)&b_lds[(j0 + 1) * 68 + og * 4];
      float4 b2 = *(const float4*)&b_lds[(j0 + 2) * 68 + og * 4];
      float4 b3 = *(const float4*)&b_lds[(j0 + 3) * 68 + og * 4];
#pragma unroll
      for (int nn = 0; nn < 4; nn++) {
        acc[nn][0] += av[nn][0]*b0.x + av[nn][1]*b1.x + av[nn][2]*b2.x + av[nn][3]*b3.x;
        acc[nn][1] += av[nn][0]*b0.y + av[nn][1]*b1.y + av[nn][2]*b2.y + av[nn][3]*b3.y;
        acc[nn][2] += av[nn][0]*b0.z + av[nn][1]*b1.z + av[nn][2]*b2.z + av[nn][3]*b3.z;
        acc[nn][3] += av[nn][0]*b0.w + av[nn][1]*b1.w + av[nn][2]*b2.w + av[nn][3]*b3.w;
      }
    }
    __syncthreads();
  }
#pragma unroll
  for (int nn = 0; nn < 4; nn++) {
    int row = n0 + ng * 4 + nn;
    float* base = out + (size_t)row * 320 + 256 + og * 4;
    atomicAdd(base + 0, acc[nn][0]);
    atomicAdd(base + 1, acc[nn][1]);
    atomicAdd(base + 2, acc[nn][2]);
    atomicAdd(base + 3, acc[nn][3]);
  }
}

extern "C" void kernel_launch(void* const* d_in, const int* in_sizes, int n_in,
                              void* d_out, int out_size, void* d_ws, size_t ws_size,
                              hipStream_t stream) {
  const float* x = (const float*)d_in[0];
  const float* affines = (const float*)d_in[1];
  const float* ne_w = (const float*)d_in[2];
  const float* lit = (const float*)d_in[3];
  const int* mask = (const int*)d_in[4];
  float* out = (float*)d_out;
  char* ws = (char*)d_ws;
  // ws layout (bytes)
  float4* pos4 = (float4*)(ws + 0);                   //  8192*16   = 131072
  float4* ncac4 = (float4*)(ws + 131072);             //  8192*48   -> 524288
  float* wt = (float*)(ws + 1179648);                 //  2048*64*4 -> 1703936
  unsigned short* enc = (unsigned short*)(ws + 1703936);  // 8192*2048*2 -> 35258368

  k_pre<<<2560, 256, 0, stream>>>((const float4*)x, affines, mask, lit, ne_w,
                                  out, pos4, ncac4, wt);
  k_knng<<<8192, 256, 0, stream>>>(pos4, affines, ncac4, out, enc);
  k_gemm<<<512, 256, 0, stream>>>(enc, wt, out);
}

// Round 8
// 194.326 us; speedup vs baseline: 1.9103x; 1.2506x over previous
//
#include <hip/hip_runtime.h>

#define NNODES 8192
#define KZ 20

// freqs[j] = 50^(-j/10)
static constexpr float FREQS[10] = {
  1.0f, 0.67624323f, 0.45730491f, 0.30924935f, 0.20912778f,
  0.14142136f, 0.09563524f, 0.06467268f, 0.04373443f, 0.02957512f};

// output offsets (floats)
#define O_XNE  0
#define O_POS  2621440
#define O_NBP  2646016
#define O_NBD  3137536
#define O_EDGE 6414336
#define O_FE   6578176

typedef __attribute__((ext_vector_type(8))) short bfrag;   // 8 bf16 (4 VGPRs)
typedef __attribute__((ext_vector_type(4))) float f32x4;   // MFMA C/D

static __device__ __forceinline__ unsigned short f2bf(float f) {
  unsigned int u = __float_as_uint(f);
  u += 0x7fffu + ((u >> 16) & 1u);
  return (unsigned short)(u >> 16);
}
static __device__ __forceinline__ unsigned int umin32(unsigned int a,
                                                      unsigned int b) {
  return a < b ? a : b;
}
// wave64 min-reduce via DPP: pure VALU, result broadcast via readlane(63).
static __device__ __forceinline__ unsigned int wave_min_u32(unsigned int v) {
  unsigned int t;
  t = (unsigned int)__builtin_amdgcn_update_dpp((int)v, (int)v, 0x111, 0xF, 0xF, false); v = umin32(v, t); // row_shr:1
  t = (unsigned int)__builtin_amdgcn_update_dpp((int)v, (int)v, 0x112, 0xF, 0xF, false); v = umin32(v, t); // row_shr:2
  t = (unsigned int)__builtin_amdgcn_update_dpp((int)v, (int)v, 0x114, 0xF, 0xF, false); v = umin32(v, t); // row_shr:4
  t = (unsigned int)__builtin_amdgcn_update_dpp((int)v, (int)v, 0x118, 0xF, 0xF, false); v = umin32(v, t); // row_shr:8
  t = (unsigned int)__builtin_amdgcn_update_dpp((int)v, (int)v, 0x142, 0xF, 0xF, false); v = umin32(v, t); // row_bcast:15
  t = (unsigned int)__builtin_amdgcn_update_dpp((int)v, (int)v, 0x143, 0xF, 0xF, false); v = umin32(v, t); // row_bcast:31
  return (unsigned int)__builtin_amdgcn_readlane((int)v, 63);
}

// ---------------- fused prep + x copy + Wt bf16 cast ----------------
__global__ __launch_bounds__(256) void k_pre(const float4* __restrict__ x4,
                                             const float* __restrict__ affines,
                                             const int* __restrict__ prot_mask,
                                             const float* __restrict__ lit,
                                             const float* __restrict__ w,
                                             float* __restrict__ out,
                                             float4* __restrict__ pos4,
                                             float4* __restrict__ ncac4,
                                             unsigned short* __restrict__ wtb) {
  int t = blockIdx.x * 256 + threadIdx.x;  // < 655360
  if (t < 524288) {  // copy x into x_ne rows (embedding cols written by gemm)
    int n = t >> 6, c = t & 63;
    ((float4*)out)[n * 80 + c] = x4[t];
  } else {  // bf16 cast of ne_weight -> wtb[64][2048] (K-contiguous, zero pad)
    int u = t - 524288;  // < 131072
    int o = u >> 11, k = u & 2047;
    wtb[u] = (k < 2000) ? f2bf(w[(size_t)o * 2000 + k]) : (unsigned short)0;
  }
  if (t < NNODES) {  // prep: positions, n2, ncac
    int n = t;
    const float4* af = (const float4*)affines + (size_t)n * 3;
    float4 a0 = af[0], a1 = af[1], a2 = af[2];  // rows of rot, .w = trans
    float tx = a0.w, ty = a1.w, tz = a2.w;
    float n2;
    {
#pragma clang fp contract(off)
      // np: sum(pos*pos,-1) = ((x*x + y*y) + z*z), each op rounded, NO fma
      float xx = tx * tx;
      float yy = ty * ty;
      float zz = tz * tz;
      n2 = (xx + yy) + zz;
    }
    pos4[n] = make_float4(tx, ty, tz, n2);
    out[O_POS + n * 3 + 0] = tx;
    out[O_POS + n * 3 + 1] = ty;
    out[O_POS + n * 3 + 2] = tz;
    int aat = (prot_mask[n] != 0) ? 0 : 20;
    const float* lp = lit + aat * 9;
#pragma unroll
    for (int a = 0; a < 3; a++) {
      float l0 = lp[a * 3 + 0], l1 = lp[a * 3 + 1], l2 = lp[a * 3 + 2];
      // ncac[a][i] = sum_j rot[i][j]*lit[a][j] + trans[i]
      float x = a0.x * l0 + a0.y * l1 + a0.z * l2 + tx;
      float y = a1.x * l0 + a1.y * l1 + a1.z * l2 + ty;
      float z = a2.x * l0 + a2.y * l1 + a2.z * l2 + tz;
      ncac4[n * 3 + a] = make_float4(x, y, z, 0.f);
    }
  }
}

// ---------------- fused KNN + gather (UNCHANGED from passing R7) ----------------
__global__ __launch_bounds__(256) void k_knng(const float4* __restrict__ pos4,
                                              const float* __restrict__ affines,
                                              const float4* __restrict__ ncac4,
                                              float* __restrict__ out,
                                              unsigned short* __restrict__ enc) {
  __shared__ unsigned long long lists[80];   // 4 waves x 20 results
  __shared__ int nidx[KZ];                   // sorted neighbor indices
  __shared__ float distbuf[100];
  int i = blockIdx.x;
  int tid = threadIdx.x;
  float4 pi = pos4[i];
  unsigned int key[32];
  unsigned int m1 = 0xFFFFFFFFu, m2 = 0xFFFFFFFFu, m3 = 0xFFFFFFFFu;
  int p1 = 0, p2 = 0, p3 = 0;
  {
#pragma clang fp contract(off)
#pragma unroll
    for (int s = 0; s < 32; s++) {
      int c = s * 256 + tid;
      float4 pc = pos4[c];
      float dot = fmaf(pi.z, pc.z, fmaf(pi.y, pc.y, pi.x * pc.x));
      float d2 = (pi.w + pc.w) - 2.0f * dot;
      unsigned int b = __float_as_uint(d2);
      unsigned int k = (b & 0x80000000u) ? ~b : (b | 0x80000000u);  // monotone map
      if (c == i) k = 0xFFFFFFFFu;  // self: never selected
      key[s] = k;
      bool c1 = k < m1, c2 = k < m2, c3 = k < m3;  // c1 implies c2 implies c3
      m3 = c2 ? m2 : (c3 ? k : m3);  p3 = c2 ? p2 : (c3 ? s : p3);
      m2 = c1 ? m1 : (c2 ? k : m2);  p2 = c1 ? p1 : (c2 ? s : p2);
      m1 = c1 ? k : m1;              p1 = c1 ? s : p1;
    }
  }
  int lane = tid & 63, w = tid >> 6;
  unsigned int ext = 0;  // extracted-candidate bitmask over s
  for (int k20 = 0; k20 < 20; k20++) {
    unsigned int mk = wave_min_u32(m1);
    unsigned long long vote = __ballot(m1 == mk);
    int src;
    if (__popcll(vote) > 1) {
      // exact key tie: winner = lowest candidate index (lex (p1,lane))
      unsigned int tb = (m1 == mk) ? (((unsigned int)p1 << 6) | (unsigned int)lane)
                                   : 0xFFFFFFFFu;
      src = (int)(wave_min_u32(tb) & 63u);
    } else {
      src = __ffsll((long long)vote) - 1;
    }
    if (lane == src) {
      int c = p1 * 256 + tid;
      lists[w * 20 + k20] = ((unsigned long long)mk << 13) | (unsigned int)c;
      ext |= 1u << p1;
      m1 = m2; p1 = p2; m2 = m3; p2 = p3; m3 = 0xFFFFFFFFu; p3 = 0;
      if (m1 == 0xFFFFFFFFu) {  // rare: rebuild top-3 from register keys
        m2 = 0xFFFFFFFFu; m3 = 0xFFFFFFFFu;
#pragma unroll
        for (int s = 0; s < 32; s++) {
          unsigned int kk = ((ext >> s) & 1u) ? 0xFFFFFFFFu : key[s];
          bool c1 = kk < m1, c2 = kk < m2, c3 = kk < m3;
          m3 = c2 ? m2 : (c3 ? kk : m3);  p3 = c2 ? p2 : (c3 ? s : p3);
          m2 = c1 ? m1 : (c2 ? kk : m2);  p2 = c1 ? p1 : (c2 ? s : p2);
          m1 = c1 ? kk : m1;              p1 = c1 ? s : p1;
        }
      }
    }
  }
  __syncthreads();
  // ---- merge 4x20 -> global top-20 by rank (u64 (key,idx): exact order) ----
  if (tid < 80) {
    unsigned long long my = lists[tid];
    int rank = 0;
    for (int t = 0; t < 80; t++) rank += (lists[t] < my) ? 1 : 0;
    if (rank < KZ) {
      int idx = (int)(my & 0x1FFFull);
      nidx[rank] = idx;
      float fi = (float)idx;
      out[O_EDGE + i * KZ + rank] = fi;                  // edge_index
      out[O_FE + i * KZ + rank] = fi;                    // full_edge row0
      out[O_FE + NNODES * KZ + i * KZ + rank] = (float)i;  // full_edge row1
    }
  }
  __syncthreads();
  // ---- gather tail: nbp, nbd, backbone distances ----
  if (tid < KZ) {
    const float4* af = (const float4*)affines + (size_t)i * 3;
    float4 a0 = af[0], a1 = af[1], a2 = af[2];
    float tx = a0.w, ty = a1.w, tz = a2.w;
    int idx = nidx[tid];
    float4 p = pos4[idx];
    float bx = p.x - tx, by = p.y - ty, bz = p.z - tz;
    // einsum('nji,nkj->nki'): v_i = sum_j rot[j][i]*b_j (rot^T; NOT orthogonal)
    float vx = a0.x * bx + a1.x * by + a2.x * bz;
    float vy = a0.y * bx + a1.y * by + a2.y * bz;
    float vz = a0.z * bx + a1.z * by + a2.z * bz;
    out[O_NBP + i * 60 + tid * 3 + 0] = vx;
    out[O_NBP + i * 60 + tid * 3 + 1] = vy;
    out[O_NBP + i * 60 + tid * 3 + 2] = vz;
    float dn = sqrtf(vx * vx + vy * vy + vz * vz);
#pragma unroll
    for (int j = 0; j < 10; j++) {
      float a = dn * FREQS[j];
      out[O_NBD + i * 400 + tid * 20 + j] = __sinf(a);
      out[O_NBD + i * 400 + tid * 20 + 10 + j] = __cosf(a);
    }
    float4 cn = ncac4[(size_t)i * 3 + 0];   // n_pos
    float4 ca = ncac4[(size_t)i * 3 + 1];   // ca_pos
    float4 cc = ncac4[(size_t)i * 3 + 2];   // c_pos
    float4 nb0 = ncac4[(size_t)idx * 3 + 0];
    float4 nb1 = ncac4[(size_t)idx * 3 + 1];
    float4 nb2 = ncac4[(size_t)idx * 3 + 2];
    auto dist = [](float4 a, float4 b) {
      float dx = a.x - b.x, dy = a.y - b.y, dz = a.z - b.z;
      return sqrtf(dx * dx + dy * dy + dz * dz);
    };
    distbuf[tid * 3 + 0] = dist(nb0, ca);
    distbuf[tid * 3 + 1] = dist(nb1, ca);
    distbuf[tid * 3 + 2] = dist(nb2, ca);
    distbuf[60 + tid] = dist(nb2, cn);  // n_to_c
    distbuf[80 + tid] = dist(nb0, cc);  // c_to_n
  }
  __syncthreads();
  // ---- enc encode (bf16), 100 cols over 256 threads ----
  unsigned short* erow = enc + (size_t)i * 2048;
  if (tid < 100) {
    float d = distbuf[tid];
    unsigned short sh[20];
#pragma unroll
    for (int j = 0; j < 10; j++) {
      float a = d * FREQS[j];
      sh[j] = f2bf(__sinf(a));
      sh[10 + j] = f2bf(__cosf(a));
    }
    unsigned int* dst = (unsigned int*)(erow + tid * 20);
#pragma unroll
    for (int wq = 0; wq < 10; wq++)
      dst[wq] = (unsigned int)sh[2 * wq] | ((unsigned int)sh[2 * wq + 1] << 16);
  } else if (tid >= 100 && tid < 124) {  // zero K-pad [2000,2048)
    unsigned int* dst = (unsigned int*)(erow + 2000 + (tid - 100) * 2);
    dst[0] = 0u;
  }
}

// ---------------- MFMA GEMM: enc(8192x2048 bf16) @ wtb^T -> x_ne[:,256:320] ----------------
// Block: 16 rows x 64 cols. 4 waves K-split (512 each), 16 K-steps x 4 mfma
// (16x16x32 bf16). A-frag: lane holds A[m=lane&15][k=(lane>>4)*8+j] straight
// from global. B-frag: wtb row n=lane&15 (K-contig) same pattern. C/D:
// col=lane&15, row=(lane>>4)*4+reg [m89/m91]. LDS reduce, plain stores.
__global__ __launch_bounds__(256) void k_gemm(const unsigned short* __restrict__ enc,
                                              const unsigned short* __restrict__ wtb,
                                              float* __restrict__ out) {
  __shared__ float red[4][16][68];  // +4 pad: conflict-free, 16B-aligned rows
  int tid = threadIdx.x;
  int w = tid >> 6, lane = tid & 63;
  int m0 = blockIdx.x * 16;
  int am = lane & 15, ak = (lane >> 4) * 8;
  const unsigned short* arow = enc + (size_t)(m0 + am) * 2048 + w * 512 + ak;
  const unsigned short* brow = wtb + (size_t)am * 2048 + w * 512 + ak;
  f32x4 acc0 = {0.f, 0.f, 0.f, 0.f}, acc1 = acc0, acc2 = acc0, acc3 = acc0;
#pragma unroll 4
  for (int ks = 0; ks < 16; ks++) {
    bfrag a = *(const bfrag*)(arow + ks * 32);
    bfrag b0 = *(const bfrag*)(brow + ks * 32);
    bfrag b1 = *(const bfrag*)(brow + 16 * 2048 + ks * 32);
    bfrag b2 = *(const bfrag*)(brow + 32 * 2048 + ks * 32);
    bfrag b3 = *(const bfrag*)(brow + 48 * 2048 + ks * 32);
    acc0 = __builtin_amdgcn_mfma_f32_16x16x32_bf16(a, b0, acc0, 0, 0, 0);
    acc1 = __builtin_amdgcn_mfma_f32_16x16x32_bf16(a, b1, acc1, 0, 0, 0);
    acc2 = __builtin_amdgcn_mfma_f32_16x16x32_bf16(a, b2, acc2, 0, 0, 0);
    acc3 = __builtin_amdgcn_mfma_f32_16x16x32_bf16(a, b3, acc3, 0, 0, 0);
  }
  {  // write partials: row=(lane>>4)*4+r, col=lane&15 (+16 per nt)
    int rm = (lane >> 4) * 4, cn = lane & 15;
#pragma unroll
    for (int r = 0; r < 4; r++) {
      red[w][rm + r][cn +  0] = acc0[r];
      red[w][rm + r][cn + 16] = acc1[r];
      red[w][rm + r][cn + 32] = acc2[r];
      red[w][rm + r][cn + 48] = acc3[r];
    }
  }
  __syncthreads();
  // reduce 4 partials; 256 threads x one float4 = 16 rows x 64 cols
  int m = tid >> 4, n = (tid & 15) * 4;
  float4 s0 = *(const float4*)&red[0][m][n];
  float4 s1 = *(const float4*)&red[1][m][n];
  float4 s2 = *(const float4*)&red[2][m][n];
  float4 s3 = *(const float4*)&red[3][m][n];
  float4 s = make_float4(s0.x + s1.x + s2.x + s3.x, s0.y + s1.y + s2.y + s3.y,
                         s0.z + s1.z + s2.z + s3.z, s0.w + s1.w + s2.w + s3.w);
  *(float4*)&out[(size_t)(m0 + m) * 320 + 256 + n] = s;
}

extern "C" void kernel_launch(void* const* d_in, const int* in_sizes, int n_in,
                              void* d_out, int out_size, void* d_ws, size_t ws_size,
                              hipStream_t stream) {
  const float* x = (const float*)d_in[0];
  const float* affines = (const float*)d_in[1];
  const float* ne_w = (const float*)d_in[2];
  const float* lit = (const float*)d_in[3];
  const int* mask = (const int*)d_in[4];
  float* out = (float*)d_out;
  char* ws = (char*)d_ws;
  // ws layout (bytes)
  float4* pos4 = (float4*)(ws + 0);                   //  8192*16   = 131072
  float4* ncac4 = (float4*)(ws + 131072);             //  8192*48   -> 524288
  unsigned short* wtb = (unsigned short*)(ws + 524288);   // 64*2048*2 -> 786432
  unsigned short* enc = (unsigned short*)(ws + 1703936);  // 8192*2048*2 -> 35258368

  k_pre<<<2560, 256, 0, stream>>>((const float4*)x, affines, mask, lit, ne_w,
                                  out, pos4, ncac4, wtb);
  k_knng<<<8192, 256, 0, stream>>>(pos4, affines, ncac4, out, enc);
  k_gemm<<<512, 256, 0, stream>>>(enc, wtb, out);
}

// Round 9
// 184.708 us; speedup vs baseline: 2.0098x; 1.0521x over previous
//
#include <hip/hip_runtime.h>

#define NNODES 8192
#define KZ 20
#define SCAP 448  // survivor cap per wave; E[n]~24 for this data, bounds-guarded

// freqs[j] = 50^(-j/10)
static constexpr float FREQS[10] = {
  1.0f, 0.67624323f, 0.45730491f, 0.30924935f, 0.20912778f,
  0.14142136f, 0.09563524f, 0.06467268f, 0.04373443f, 0.02957512f};

// output offsets (floats)
#define O_XNE  0
#define O_POS  2621440
#define O_NBP  2646016
#define O_NBD  3137536
#define O_EDGE 6414336
#define O_FE   6578176

typedef __attribute__((ext_vector_type(8))) short bfrag;   // 8 bf16 (4 VGPRs)
typedef __attribute__((ext_vector_type(4))) float f32x4;   // MFMA C/D

static __device__ __forceinline__ unsigned short f2bf(float f) {
  unsigned int u = __float_as_uint(f);
  u += 0x7fffu + ((u >> 16) & 1u);
  return (unsigned short)(u >> 16);
}
static __device__ __forceinline__ unsigned int umin32(unsigned int a,
                                                      unsigned int b) {
  return a < b ? a : b;
}
// wave64 min-reduce via DPP: pure VALU, result broadcast via readlane(63).
static __device__ __forceinline__ unsigned int wave_min_u32(unsigned int v) {
  unsigned int t;
  t = (unsigned int)__builtin_amdgcn_update_dpp((int)v, (int)v, 0x111, 0xF, 0xF, false); v = umin32(v, t); // row_shr:1
  t = (unsigned int)__builtin_amdgcn_update_dpp((int)v, (int)v, 0x112, 0xF, 0xF, false); v = umin32(v, t); // row_shr:2
  t = (unsigned int)__builtin_amdgcn_update_dpp((int)v, (int)v, 0x114, 0xF, 0xF, false); v = umin32(v, t); // row_shr:4
  t = (unsigned int)__builtin_amdgcn_update_dpp((int)v, (int)v, 0x118, 0xF, 0xF, false); v = umin32(v, t); // row_shr:8
  t = (unsigned int)__builtin_amdgcn_update_dpp((int)v, (int)v, 0x142, 0xF, 0xF, false); v = umin32(v, t); // row_bcast:15
  t = (unsigned int)__builtin_amdgcn_update_dpp((int)v, (int)v, 0x143, 0xF, 0xF, false); v = umin32(v, t); // row_bcast:31
  return (unsigned int)__builtin_amdgcn_readlane((int)v, 63);
}

// ---------------- fused prep + x copy + Wt bf16 cast (UNCHANGED R8) ----------------
__global__ __launch_bounds__(256) void k_pre(const float4* __restrict__ x4,
                                             const float* __restrict__ affines,
                                             const int* __restrict__ prot_mask,
                                             const float* __restrict__ lit,
                                             const float* __restrict__ w,
                                             float* __restrict__ out,
                                             float4* __restrict__ pos4,
                                             float4* __restrict__ ncac4,
                                             unsigned short* __restrict__ wtb) {
  int t = blockIdx.x * 256 + threadIdx.x;  // < 655360
  if (t < 524288) {  // copy x into x_ne rows (embedding cols written by gemm)
    int n = t >> 6, c = t & 63;
    ((float4*)out)[n * 80 + c] = x4[t];
  } else {  // bf16 cast of ne_weight -> wtb[64][2048] (K-contiguous, zero pad)
    int u = t - 524288;  // < 131072
    int o = u >> 11, k = u & 2047;
    wtb[u] = (k < 2000) ? f2bf(w[(size_t)o * 2000 + k]) : (unsigned short)0;
  }
  if (t < NNODES) {  // prep: positions, n2, ncac
    int n = t;
    const float4* af = (const float4*)affines + (size_t)n * 3;
    float4 a0 = af[0], a1 = af[1], a2 = af[2];  // rows of rot, .w = trans
    float tx = a0.w, ty = a1.w, tz = a2.w;
    float n2;
    {
#pragma clang fp contract(off)
      // np: sum(pos*pos,-1) = ((x*x + y*y) + z*z), each op rounded, NO fma
      float xx = tx * tx;
      float yy = ty * ty;
      float zz = tz * tz;
      n2 = (xx + yy) + zz;
    }
    pos4[n] = make_float4(tx, ty, tz, n2);
    out[O_POS + n * 3 + 0] = tx;
    out[O_POS + n * 3 + 1] = ty;
    out[O_POS + n * 3 + 2] = tz;
    int aat = (prot_mask[n] != 0) ? 0 : 20;
    const float* lp = lit + aat * 9;
#pragma unroll
    for (int a = 0; a < 3; a++) {
      float l0 = lp[a * 3 + 0], l1 = lp[a * 3 + 1], l2 = lp[a * 3 + 2];
      // ncac[a][i] = sum_j rot[i][j]*lit[a][j] + trans[i]
      float x = a0.x * l0 + a0.y * l1 + a0.z * l2 + tx;
      float y = a1.x * l0 + a1.y * l1 + a1.z * l2 + ty;
      float z = a2.x * l0 + a2.y * l1 + a2.z * l2 + tz;
      ncac4[n * 3 + a] = make_float4(x, y, z, 0.f);
    }
  }
}

// ---------------- fused KNN + gather: pivot-filter selection ----------------
// d2/key arithmetic bit-identical to the passing version:
//   dot = fmaf(z_i,z_j, fmaf(y_i,y_j, x_i*x_j)); d2 = (n2_i+n2_j) - 2*dot
// Phase 1: scan keeps only per-lane min (keys parked in VGPRs).
// Phase 2: pivot = knockout-reduce lane minima until >=20 lanes removed
//          => >=20 distinct elements <= pivot (sound upper bound on 20th).
// Phase 3: compact survivors (key <= pivot) to LDS u64 (key<<13|c).
// Phase 4: exact rank among survivors -> wave top-20 -> 80-item merge.
__global__ __launch_bounds__(256) void k_knng(const float4* __restrict__ pos4,
                                              const float* __restrict__ affines,
                                              const float4* __restrict__ ncac4,
                                              float* __restrict__ out,
                                              unsigned short* __restrict__ enc) {
  __shared__ unsigned long long surv[4][SCAP];  // 14 KB survivors
  __shared__ unsigned long long lists[80];      // 4 waves x 20 results
  __shared__ int nidx[KZ];
  __shared__ float distbuf[100];
  int i = blockIdx.x;
  int tid = threadIdx.x;
  int lane = tid & 63, w = tid >> 6;
  float4 pi = pos4[i];
  unsigned int key[32];
  unsigned int lmin = 0xFFFFFFFFu;
  {
#pragma clang fp contract(off)
#pragma unroll
    for (int s = 0; s < 32; s++) {
      int c = s * 256 + tid;
      float4 pc = pos4[c];
      float dot = fmaf(pi.z, pc.z, fmaf(pi.y, pc.y, pi.x * pc.x));
      float d2 = (pi.w + pc.w) - 2.0f * dot;
      unsigned int b = __float_as_uint(d2);
      unsigned int k = (b & 0x80000000u) ? ~b : (b | 0x80000000u);  // monotone map
      if (c == i) k = 0xFFFFFFFFu;  // self: never selected
      key[s] = k;
      lmin = umin32(lmin, k);
    }
  }
  // ---- phase 2: sound pivot from lane minima (<=20 DPP rounds) ----
  unsigned int pivot;
  {
    unsigned int m = lmin;
    int removed = 0;
    do {
      pivot = wave_min_u32(m);
      unsigned long long tie = __ballot(m == pivot);
      removed += __popcll(tie);
      if (m == pivot) m = 0xFFFFFFFFu;
    } while (removed < KZ);
  }
  // ---- phase 3: compact survivors (key <= pivot) into LDS ----
  unsigned int base = 0;
#pragma unroll
  for (int s = 0; s < 32; s++) {
    unsigned long long mask = __ballot(key[s] <= pivot);
    if (mask) {
      unsigned int ofs = __builtin_amdgcn_mbcnt_lo((unsigned int)mask, 0u);
      ofs = __builtin_amdgcn_mbcnt_hi((unsigned int)(mask >> 32), ofs);
      if (key[s] <= pivot) {
        unsigned int idx = base + ofs;
        if (idx < SCAP) {  // bounds guard (never hit for this data)
          unsigned int c = (unsigned int)(s * 256 + tid);
          surv[w][idx] = ((unsigned long long)key[s] << 13) | c;
        }
      }
      base += (unsigned int)__popcll(mask);
    }
  }
  unsigned int n = base < SCAP ? base : SCAP;
  __builtin_amdgcn_s_waitcnt(0);   // drain LDS writes (wave-local view)
  __builtin_amdgcn_wave_barrier();
  // ---- phase 4: exact rank among survivors -> wave top-20 ----
  for (unsigned int j = lane; j < n; j += 64) {
    unsigned long long my = surv[w][j];
    int rank = 0;
    for (unsigned int t = 0; t < n; t++) rank += (surv[w][t] < my) ? 1 : 0;
    if (rank < KZ) lists[w * 20 + rank] = my;
  }
  __syncthreads();
  // ---- merge 4x20 -> global top-20 by rank (u64 (key,c): exact order) ----
  if (tid < 80) {
    unsigned long long my = lists[tid];
    int rank = 0;
    for (int t = 0; t < 80; t++) rank += (lists[t] < my) ? 1 : 0;
    if (rank < KZ) {
      int idx = (int)(my & 0x1FFFull);
      nidx[rank] = idx;
      float fi = (float)idx;
      out[O_EDGE + i * KZ + rank] = fi;                  // edge_index
      out[O_FE + i * KZ + rank] = fi;                    // full_edge row0
      out[O_FE + NNODES * KZ + i * KZ + rank] = (float)i;  // full_edge row1
    }
  }
  __syncthreads();
  // ---- gather tail: nbp, nbd, backbone distances (UNCHANGED) ----
  if (tid < KZ) {
    const float4* af = (const float4*)affines + (size_t)i * 3;
    float4 a0 = af[0], a1 = af[1], a2 = af[2];
    float tx = a0.w, ty = a1.w, tz = a2.w;
    int idx = nidx[tid];
    float4 p = pos4[idx];
    float bx = p.x - tx, by = p.y - ty, bz = p.z - tz;
    // einsum('nji,nkj->nki'): v_i = sum_j rot[j][i]*b_j (rot^T; NOT orthogonal)
    float vx = a0.x * bx + a1.x * by + a2.x * bz;
    float vy = a0.y * bx + a1.y * by + a2.y * bz;
    float vz = a0.z * bx + a1.z * by + a2.z * bz;
    out[O_NBP + i * 60 + tid * 3 + 0] = vx;
    out[O_NBP + i * 60 + tid * 3 + 1] = vy;
    out[O_NBP + i * 60 + tid * 3 + 2] = vz;
    float dn = sqrtf(vx * vx + vy * vy + vz * vz);
#pragma unroll
    for (int j = 0; j < 10; j++) {
      float a = dn * FREQS[j];
      out[O_NBD + i * 400 + tid * 20 + j] = __sinf(a);
      out[O_NBD + i * 400 + tid * 20 + 10 + j] = __cosf(a);
    }
    float4 cn = ncac4[(size_t)i * 3 + 0];   // n_pos
    float4 ca = ncac4[(size_t)i * 3 + 1];   // ca_pos
    float4 cc = ncac4[(size_t)i * 3 + 2];   // c_pos
    float4 nb0 = ncac4[(size_t)idx * 3 + 0];
    float4 nb1 = ncac4[(size_t)idx * 3 + 1];
    float4 nb2 = ncac4[(size_t)idx * 3 + 2];
    auto dist = [](float4 a, float4 b) {
      float dx = a.x - b.x, dy = a.y - b.y, dz = a.z - b.z;
      return sqrtf(dx * dx + dy * dy + dz * dz);
    };
    distbuf[tid * 3 + 0] = dist(nb0, ca);
    distbuf[tid * 3 + 1] = dist(nb1, ca);
    distbuf[tid * 3 + 2] = dist(nb2, ca);
    distbuf[60 + tid] = dist(nb2, cn);  // n_to_c
    distbuf[80 + tid] = dist(nb0, cc);  // c_to_n
  }
  __syncthreads();
  // ---- enc encode (bf16), 100 cols over 256 threads ----
  unsigned short* erow = enc + (size_t)i * 2048;
  if (tid < 100) {
    float d = distbuf[tid];
    unsigned short sh[20];
#pragma unroll
    for (int j = 0; j < 10; j++) {
      float a = d * FREQS[j];
      sh[j] = f2bf(__sinf(a));
      sh[10 + j] = f2bf(__cosf(a));
    }
    unsigned int* dst = (unsigned int*)(erow + tid * 20);
#pragma unroll
    for (int wq = 0; wq < 10; wq++)
      dst[wq] = (unsigned int)sh[2 * wq] | ((unsigned int)sh[2 * wq + 1] << 16);
  } else if (tid >= 100 && tid < 124) {  // zero K-pad [2000,2048)
    unsigned int* dst = (unsigned int*)(erow + 2000 + (tid - 100) * 2);
    dst[0] = 0u;
  }
}

// ---------------- MFMA GEMM (UNCHANGED R8) ----------------
__global__ __launch_bounds__(256) void k_gemm(const unsigned short* __restrict__ enc,
                                              const unsigned short* __restrict__ wtb,
                                              float* __restrict__ out) {
  __shared__ float red[4][16][68];  // +4 pad: conflict-free, 16B-aligned rows
  int tid = threadIdx.x;
  int w = tid >> 6, lane = tid & 63;
  int m0 = blockIdx.x * 16;
  int am = lane & 15, ak = (lane >> 4) * 8;
  const unsigned short* arow = enc + (size_t)(m0 + am) * 2048 + w * 512 + ak;
  const unsigned short* brow = wtb + (size_t)am * 2048 + w * 512 + ak;
  f32x4 acc0 = {0.f, 0.f, 0.f, 0.f}, acc1 = acc0, acc2 = acc0, acc3 = acc0;
#pragma unroll 4
  for (int ks = 0; ks < 16; ks++) {
    bfrag a = *(const bfrag*)(arow + ks * 32);
    bfrag b0 = *(const bfrag*)(brow + ks * 32);
    bfrag b1 = *(const bfrag*)(brow + 16 * 2048 + ks * 32);
    bfrag b2 = *(const bfrag*)(brow + 32 * 2048 + ks * 32);
    bfrag b3 = *(const bfrag*)(brow + 48 * 2048 + ks * 32);
    acc0 = __builtin_amdgcn_mfma_f32_16x16x32_bf16(a, b0, acc0, 0, 0, 0);
    acc1 = __builtin_amdgcn_mfma_f32_16x16x32_bf16(a, b1, acc1, 0, 0, 0);
    acc2 = __builtin_amdgcn_mfma_f32_16x16x32_bf16(a, b2, acc2, 0, 0, 0);
    acc3 = __builtin_amdgcn_mfma_f32_16x16x32_bf16(a, b3, acc3, 0, 0, 0);
  }
  {  // write partials: row=(lane>>4)*4+r, col=lane&15 (+16 per nt)
    int rm = (lane >> 4) * 4, cn = lane & 15;
#pragma unroll
    for (int r = 0; r < 4; r++) {
      red[w][rm + r][cn +  0] = acc0[r];
      red[w][rm + r][cn + 16] = acc1[r];
      red[w][rm + r][cn + 32] = acc2[r];
      red[w][rm + r][cn + 48] = acc3[r];
    }
  }
  __syncthreads();
  // reduce 4 partials; 256 threads x one float4 = 16 rows x 64 cols
  int m = tid >> 4, n = (tid & 15) * 4;
  float4 s0 = *(const float4*)&red[0][m][n];
  float4 s1 = *(const float4*)&red[1][m][n];
  float4 s2 = *(const float4*)&red[2][m][n];
  float4 s3 = *(const float4*)&red[3][m][n];
  float4 s = make_float4(s0.x + s1.x + s2.x + s3.x, s0.y + s1.y + s2.y + s3.y,
                         s0.z + s1.z + s2.z + s3.z, s0.w + s1.w + s2.w + s3.w);
  *(float4*)&out[(size_t)(m0 + m) * 320 + 256 + n] = s;
}

extern "C" void kernel_launch(void* const* d_in, const int* in_sizes, int n_in,
                              void* d_out, int out_size, void* d_ws, size_t ws_size,
                              hipStream_t stream) {
  const float* x = (const float*)d_in[0];
  const float* affines = (const float*)d_in[1];
  const float* ne_w = (const float*)d_in[2];
  const float* lit = (const float*)d_in[3];
  const int* mask = (const int*)d_in[4];
  float* out = (float*)d_out;
  char* ws = (char*)d_ws;
  // ws layout (bytes)
  float4* pos4 = (float4*)(ws + 0);                   //  8192*16   = 131072
  float4* ncac4 = (float4*)(ws + 131072);             //  8192*48   -> 524288
  unsigned short* wtb = (unsigned short*)(ws + 524288);   // 64*2048*2 -> 786432
  unsigned short* enc = (unsigned short*)(ws + 1703936);  // 8192*2048*2 -> 35258368

  k_pre<<<2560, 256, 0, stream>>>((const float4*)x, affines, mask, lit, ne_w,
                                  out, pos4, ncac4, wtb);
  k_knng<<<8192, 256, 0, stream>>>(pos4, affines, ncac4, out, enc);
  k_gemm<<<512, 256, 0, stream>>>(enc, wtb, out);
}

// Round 10
// 156.788 us; speedup vs baseline: 2.3677x; 1.1781x over previous
//
#include <hip/hip_runtime.h>

#define NNODES 8192
#define KZ 20
#define SCAP 448  // survivor cap per wave; E[n]~24 for this data, bounds-guarded

// freqs[j] = 50^(-j/10)
static constexpr float FREQS[10] = {
  1.0f, 0.67624323f, 0.45730491f, 0.30924935f, 0.20912778f,
  0.14142136f, 0.09563524f, 0.06467268f, 0.04373443f, 0.02957512f};

// output offsets (floats)
#define O_XNE  0
#define O_POS  2621440
#define O_NBP  2646016
#define O_NBD  3137536
#define O_EDGE 6414336
#define O_FE   6578176

typedef __attribute__((ext_vector_type(8))) short bfrag;   // 8 bf16 (4 VGPRs)
typedef __attribute__((ext_vector_type(4))) float f32x4;   // MFMA C/D

static __device__ __forceinline__ unsigned short f2bf(float f) {
  unsigned int u = __float_as_uint(f);
  u += 0x7fffu + ((u >> 16) & 1u);
  return (unsigned short)(u >> 16);
}
// wave64 max-reduce via DPP (same verified pattern as the R6-R9 min-reduce).
static __device__ __forceinline__ float wave_max_f32(float v) {
  float t;
  t = __builtin_bit_cast(float, __builtin_amdgcn_update_dpp(__builtin_bit_cast(int, v), __builtin_bit_cast(int, v), 0x111, 0xF, 0xF, false)); v = fmaxf(v, t); // row_shr:1
  t = __builtin_bit_cast(float, __builtin_amdgcn_update_dpp(__builtin_bit_cast(int, v), __builtin_bit_cast(int, v), 0x112, 0xF, 0xF, false)); v = fmaxf(v, t); // row_shr:2
  t = __builtin_bit_cast(float, __builtin_amdgcn_update_dpp(__builtin_bit_cast(int, v), __builtin_bit_cast(int, v), 0x114, 0xF, 0xF, false)); v = fmaxf(v, t); // row_shr:4
  t = __builtin_bit_cast(float, __builtin_amdgcn_update_dpp(__builtin_bit_cast(int, v), __builtin_bit_cast(int, v), 0x118, 0xF, 0xF, false)); v = fmaxf(v, t); // row_shr:8
  t = __builtin_bit_cast(float, __builtin_amdgcn_update_dpp(__builtin_bit_cast(int, v), __builtin_bit_cast(int, v), 0x142, 0xF, 0xF, false)); v = fmaxf(v, t); // row_bcast:15
  t = __builtin_bit_cast(float, __builtin_amdgcn_update_dpp(__builtin_bit_cast(int, v), __builtin_bit_cast(int, v), 0x143, 0xF, 0xF, false)); v = fmaxf(v, t); // row_bcast:31
  return __builtin_bit_cast(float, __builtin_amdgcn_readlane(__builtin_bit_cast(int, v), 63));
}

// ---------------- fused prep + x copy + Wt bf16 cast (UNCHANGED R8) ----------------
__global__ __launch_bounds__(256) void k_pre(const float4* __restrict__ x4,
                                             const float* __restrict__ affines,
                                             const int* __restrict__ prot_mask,
                                             const float* __restrict__ lit,
                                             const float* __restrict__ w,
                                             float* __restrict__ out,
                                             float4* __restrict__ pos4,
                                             float4* __restrict__ ncac4,
                                             unsigned short* __restrict__ wtb) {
  int t = blockIdx.x * 256 + threadIdx.x;  // < 655360
  if (t < 524288) {  // copy x into x_ne rows (embedding cols written by gemm)
    int n = t >> 6, c = t & 63;
    ((float4*)out)[n * 80 + c] = x4[t];
  } else {  // bf16 cast of ne_weight -> wtb[64][2048] (K-contiguous, zero pad)
    int u = t - 524288;  // < 131072
    int o = u >> 11, k = u & 2047;
    wtb[u] = (k < 2000) ? f2bf(w[(size_t)o * 2000 + k]) : (unsigned short)0;
  }
  if (t < NNODES) {  // prep: positions, n2, ncac
    int n = t;
    const float4* af = (const float4*)affines + (size_t)n * 3;
    float4 a0 = af[0], a1 = af[1], a2 = af[2];  // rows of rot, .w = trans
    float tx = a0.w, ty = a1.w, tz = a2.w;
    float n2;
    {
#pragma clang fp contract(off)
      // np: sum(pos*pos,-1) = ((x*x + y*y) + z*z), each op rounded, NO fma
      float xx = tx * tx;
      float yy = ty * ty;
      float zz = tz * tz;
      n2 = (xx + yy) + zz;
    }
    pos4[n] = make_float4(tx, ty, tz, n2);
    out[O_POS + n * 3 + 0] = tx;
    out[O_POS + n * 3 + 1] = ty;
    out[O_POS + n * 3 + 2] = tz;
    int aat = (prot_mask[n] != 0) ? 0 : 20;
    const float* lp = lit + aat * 9;
#pragma unroll
    for (int a = 0; a < 3; a++) {
      float l0 = lp[a * 3 + 0], l1 = lp[a * 3 + 1], l2 = lp[a * 3 + 2];
      // ncac[a][i] = sum_j rot[i][j]*lit[a][j] + trans[i]
      float x = a0.x * l0 + a0.y * l1 + a0.z * l2 + tx;
      float y = a1.x * l0 + a1.y * l1 + a1.z * l2 + ty;
      float z = a2.x * l0 + a2.y * l1 + a2.z * l2 + tz;
      ncac4[n * 3 + a] = make_float4(x, y, z, 0.f);
    }
  }
}

// ---------------- fused KNN + gather: float-domain pivot-filter ----------------
// d2 arithmetic bit-identical to all passing rounds:
//   dot = fmaf(z_i,z_j, fmaf(y_i,y_j, x_i*x_j)); d2 = (n2_i+n2_j) - 2*dot
// d2 is compared in FLOAT domain during scan/filter (valid: all finite, -0.0
// unreachable since a-b==0 -> +0.0); the sortable-int map is applied only to
// the ~24 survivors, so final (key,idx) ranking is identical to R9.
// Pivot = exact 20th-smallest of the 64 per-lane minima (throughput version:
// LDS strict-rank count + one DPP max) => >=20 elements <= pivot (sound).
__global__ __launch_bounds__(256) void k_knng(const float4* __restrict__ pos4,
                                              const float* __restrict__ affines,
                                              const float4* __restrict__ ncac4,
                                              float* __restrict__ out,
                                              unsigned short* __restrict__ enc) {
  __shared__ unsigned long long surv[4][SCAP];  // 14 KB survivors
  __shared__ unsigned long long lists[80];      // 4 waves x 20 results
  __shared__ float minb[4][64];                 // per-wave lane minima
  __shared__ int nidx[KZ];
  __shared__ float distbuf[100];
  int i = blockIdx.x;
  int tid = threadIdx.x;
  int lane = tid & 63, w = tid >> 6;
  float4 pi = pos4[i];
  float d2v[32];
  float lmin = __builtin_inff();
  int s_self = i >> 8;
  bool me = (tid == (i & 255));
  {
#pragma clang fp contract(off)
#pragma unroll
    for (int s = 0; s < 32; s++) {
      float4 pc = pos4[s * 256 + tid];
      float dot = fmaf(pi.z, pc.z, fmaf(pi.y, pc.y, pi.x * pc.x));
      float d2 = (pi.w + pc.w) - 2.0f * dot;
      if (s == s_self && me) d2 = __builtin_inff();  // self: never selected
      d2v[s] = d2;
      lmin = fminf(lmin, d2);
    }
  }
  // ---- pivot: exact 20th-smallest lane minimum (throughput, no serial loop) ----
  minb[w][lane] = lmin;
  __builtin_amdgcn_s_waitcnt(0);
  __builtin_amdgcn_wave_barrier();
  int cnt = 0;
#pragma unroll 8
  for (int j = 0; j < 64; j++) cnt += (minb[w][j] < lmin) ? 1 : 0;
  float elig = (cnt < KZ) ? lmin : -__builtin_inff();
  float pivot = wave_max_f32(elig);
  // ---- compact survivors (d2 <= pivot) into LDS, skipping empty steps ----
  unsigned int base = 0;
#pragma unroll
  for (int s = 0; s < 32; s++) {
    bool p = d2v[s] <= pivot;
    unsigned long long mask = __ballot(p);
    if (mask) {  // wave-uniform branch: most steps have no survivor
      if (p) {
        unsigned int ofs = __builtin_amdgcn_mbcnt_lo((unsigned int)mask, 0u);
        ofs = __builtin_amdgcn_mbcnt_hi((unsigned int)(mask >> 32), ofs);
        unsigned int idx = base + ofs;
        if (idx < SCAP) {  // bounds guard (never hit for this data)
          unsigned int b = __float_as_uint(d2v[s]);
          unsigned int k = (b & 0x80000000u) ? ~b : (b | 0x80000000u);
          unsigned int c = (unsigned int)(s * 256 + tid);
          surv[w][idx] = ((unsigned long long)k << 13) | c;
        }
      }
      base += (unsigned int)__popcll(mask);
    }
  }
  unsigned int n = base < SCAP ? base : SCAP;
  __builtin_amdgcn_s_waitcnt(0);   // drain LDS writes (wave-local view)
  __builtin_amdgcn_wave_barrier();
  // ---- exact rank among survivors -> wave top-20 ----
  for (unsigned int j = lane; j < n; j += 64) {
    unsigned long long my = surv[w][j];
    int rank = 0;
    for (unsigned int t = 0; t < n; t++) rank += (surv[w][t] < my) ? 1 : 0;
    if (rank < KZ) lists[w * 20 + rank] = my;
  }
  __syncthreads();
  // ---- merge 4x20 -> global top-20 by rank (u64 (key,c): exact order) ----
  if (tid < 80) {
    unsigned long long my = lists[tid];
    int rank = 0;
    for (int t = 0; t < 80; t++) rank += (lists[t] < my) ? 1 : 0;
    if (rank < KZ) {
      int idx = (int)(my & 0x1FFFull);
      nidx[rank] = idx;
      float fi = (float)idx;
      out[O_EDGE + i * KZ + rank] = fi;                  // edge_index
      out[O_FE + i * KZ + rank] = fi;                    // full_edge row0
      out[O_FE + NNODES * KZ + i * KZ + rank] = (float)i;  // full_edge row1
    }
  }
  __syncthreads();
  // ---- gather tail: nbp, nbd, backbone distances (UNCHANGED) ----
  if (tid < KZ) {
    const float4* af = (const float4*)affines + (size_t)i * 3;
    float4 a0 = af[0], a1 = af[1], a2 = af[2];
    float tx = a0.w, ty = a1.w, tz = a2.w;
    int idx = nidx[tid];
    float4 p = pos4[idx];
    float bx = p.x - tx, by = p.y - ty, bz = p.z - tz;
    // einsum('nji,nkj->nki'): v_i = sum_j rot[j][i]*b_j (rot^T; NOT orthogonal)
    float vx = a0.x * bx + a1.x * by + a2.x * bz;
    float vy = a0.y * bx + a1.y * by + a2.y * bz;
    float vz = a0.z * bx + a1.z * by + a2.z * bz;
    out[O_NBP + i * 60 + tid * 3 + 0] = vx;
    out[O_NBP + i * 60 + tid * 3 + 1] = vy;
    out[O_NBP + i * 60 + tid * 3 + 2] = vz;
    float dn = sqrtf(vx * vx + vy * vy + vz * vz);
#pragma unroll
    for (int j = 0; j < 10; j++) {
      float a = dn * FREQS[j];
      out[O_NBD + i * 400 + tid * 20 + j] = __sinf(a);
      out[O_NBD + i * 400 + tid * 20 + 10 + j] = __cosf(a);
    }
    float4 cn = ncac4[(size_t)i * 3 + 0];   // n_pos
    float4 ca = ncac4[(size_t)i * 3 + 1];   // ca_pos
    float4 cc = ncac4[(size_t)i * 3 + 2];   // c_pos
    float4 nb0 = ncac4[(size_t)idx * 3 + 0];
    float4 nb1 = ncac4[(size_t)idx * 3 + 1];
    float4 nb2 = ncac4[(size_t)idx * 3 + 2];
    auto dist = [](float4 a, float4 b) {
      float dx = a.x - b.x, dy = a.y - b.y, dz = a.z - b.z;
      return sqrtf(dx * dx + dy * dy + dz * dz);
    };
    distbuf[tid * 3 + 0] = dist(nb0, ca);
    distbuf[tid * 3 + 1] = dist(nb1, ca);
    distbuf[tid * 3 + 2] = dist(nb2, ca);
    distbuf[60 + tid] = dist(nb2, cn);  // n_to_c
    distbuf[80 + tid] = dist(nb0, cc);  // c_to_n
  }
  __syncthreads();
  // ---- enc encode (bf16), 100 cols over 256 threads ----
  unsigned short* erow = enc + (size_t)i * 2048;
  if (tid < 100) {
    float d = distbuf[tid];
    unsigned short sh[20];
#pragma unroll
    for (int j = 0; j < 10; j++) {
      float a = d * FREQS[j];
      sh[j] = f2bf(__sinf(a));
      sh[10 + j] = f2bf(__cosf(a));
    }
    unsigned int* dst = (unsigned int*)(erow + tid * 20);
#pragma unroll
    for (int wq = 0; wq < 10; wq++)
      dst[wq] = (unsigned int)sh[2 * wq] | ((unsigned int)sh[2 * wq + 1] << 16);
  } else if (tid >= 100 && tid < 124) {  // zero K-pad [2000,2048)
    unsigned int* dst = (unsigned int*)(erow + 2000 + (tid - 100) * 2);
    dst[0] = 0u;
  }
}

// ---------------- MFMA GEMM (UNCHANGED R8) ----------------
__global__ __launch_bounds__(256) void k_gemm(const unsigned short* __restrict__ enc,
                                              const unsigned short* __restrict__ wtb,
                                              float* __restrict__ out) {
  __shared__ float red[4][16][68];  // +4 pad: conflict-free, 16B-aligned rows
  int tid = threadIdx.x;
  int w = tid >> 6, lane = tid & 63;
  int m0 = blockIdx.x * 16;
  int am = lane & 15, ak = (lane >> 4) * 8;
  const unsigned short* arow = enc + (size_t)(m0 + am) * 2048 + w * 512 + ak;
  const unsigned short* brow = wtb + (size_t)am * 2048 + w * 512 + ak;
  f32x4 acc0 = {0.f, 0.f, 0.f, 0.f}, acc1 = acc0, acc2 = acc0, acc3 = acc0;
#pragma unroll 4
  for (int ks = 0; ks < 16; ks++) {
    bfrag a = *(const bfrag*)(arow + ks * 32);
    bfrag b0 = *(const bfrag*)(brow + ks * 32);
    bfrag b1 = *(const bfrag*)(brow + 16 * 2048 + ks * 32);
    bfrag b2 = *(const bfrag*)(brow + 32 * 2048 + ks * 32);
    bfrag b3 = *(const bfrag*)(brow + 48 * 2048 + ks * 32);
    acc0 = __builtin_amdgcn_mfma_f32_16x16x32_bf16(a, b0, acc0, 0, 0, 0);
    acc1 = __builtin_amdgcn_mfma_f32_16x16x32_bf16(a, b1, acc1, 0, 0, 0);
    acc2 = __builtin_amdgcn_mfma_f32_16x16x32_bf16(a, b2, acc2, 0, 0, 0);
    acc3 = __builtin_amdgcn_mfma_f32_16x16x32_bf16(a, b3, acc3, 0, 0, 0);
  }
  {  // write partials: row=(lane>>4)*4+r, col=lane&15 (+16 per nt)
    int rm = (lane >> 4) * 4, cn = lane & 15;
#pragma unroll
    for (int r = 0; r < 4; r++) {
      red[w][rm + r][cn +  0] = acc0[r];
      red[w][rm + r][cn + 16] = acc1[r];
      red[w][rm + r][cn + 32] = acc2[r];
      red[w][rm + r][cn + 48] = acc3[r];
    }
  }
  __syncthreads();
  // reduce 4 partials; 256 threads x one float4 = 16 rows x 64 cols
  int m = tid >> 4, n = (tid & 15) * 4;
  float4 s0 = *(const float4*)&red[0][m][n];
  float4 s1 = *(const float4*)&red[1][m][n];
  float4 s2 = *(const float4*)&red[2][m][n];
  float4 s3 = *(const float4*)&red[3][m][n];
  float4 s = make_float4(s0.x + s1.x + s2.x + s3.x, s0.y + s1.y + s2.y + s3.y,
                         s0.z + s1.z + s2.z + s3.z, s0.w + s1.w + s2.w + s3.w);
  *(float4*)&out[(size_t)(m0 + m) * 320 + 256 + n] = s;
}

extern "C" void kernel_launch(void* const* d_in, const int* in_sizes, int n_in,
                              void* d_out, int out_size, void* d_ws, size_t ws_size,
                              hipStream_t stream) {
  const float* x = (const float*)d_in[0];
  const float* affines = (const float*)d_in[1];
  const float* ne_w = (const float*)d_in[2];
  const float* lit = (const float*)d_in[3];
  const int* mask = (const int*)d_in[4];
  float* out = (float*)d_out;
  char* ws = (char*)d_ws;
  // ws layout (bytes)
  float4* pos4 = (float4*)(ws + 0);                   //  8192*16   = 131072
  float4* ncac4 = (float4*)(ws + 131072);             //  8192*48   -> 524288
  unsigned short* wtb = (unsigned short*)(ws + 524288);   // 64*2048*2 -> 786432
  unsigned short* enc = (unsigned short*)(ws + 1703936);  // 8192*2048*2 -> 35258368

  k_pre<<<2560, 256, 0, stream>>>((const float4*)x, affines, mask, lit, ne_w,
                                  out, pos4, ncac4, wtb);
  k_knng<<<8192, 256, 0, stream>>>(pos4, affines, ncac4, out, enc);
  k_gemm<<<512, 256, 0, stream>>>(enc, wtb, out);
}

// Round 11
// 142.845 us; speedup vs baseline: 2.5988x; 1.0976x over previous
//
#include <hip/hip_runtime.h>

#define NNODES 8192
#define KZ 20
#define QB 4      // queries per block
#define SCAP 192  // survivor cap per query; E[n]~45, bounds-guarded

// freqs[j] = 50^(-j/10)
static constexpr float FREQS[10] = {
  1.0f, 0.67624323f, 0.45730491f, 0.30924935f, 0.20912778f,
  0.14142136f, 0.09563524f, 0.06467268f, 0.04373443f, 0.02957512f};

// output offsets (floats)
#define O_XNE  0
#define O_POS  2621440
#define O_NBP  2646016
#define O_NBD  3137536
#define O_EDGE 6414336
#define O_FE   6578176

typedef __attribute__((ext_vector_type(8))) short bfrag;   // 8 bf16 (4 VGPRs)
typedef __attribute__((ext_vector_type(4))) float f32x4;   // MFMA C/D

static __device__ __forceinline__ unsigned short f2bf(float f) {
  unsigned int u = __float_as_uint(f);
  u += 0x7fffu + ((u >> 16) & 1u);
  return (unsigned short)(u >> 16);
}
// wave64 max-reduce via DPP (verified pattern since R6), broadcast to all lanes.
static __device__ __forceinline__ float wave_max_f32(float v) {
  float t;
  t = __builtin_bit_cast(float, __builtin_amdgcn_update_dpp(__builtin_bit_cast(int, v), __builtin_bit_cast(int, v), 0x111, 0xF, 0xF, false)); v = fmaxf(v, t); // row_shr:1
  t = __builtin_bit_cast(float, __builtin_amdgcn_update_dpp(__builtin_bit_cast(int, v), __builtin_bit_cast(int, v), 0x112, 0xF, 0xF, false)); v = fmaxf(v, t); // row_shr:2
  t = __builtin_bit_cast(float, __builtin_amdgcn_update_dpp(__builtin_bit_cast(int, v), __builtin_bit_cast(int, v), 0x114, 0xF, 0xF, false)); v = fmaxf(v, t); // row_shr:4
  t = __builtin_bit_cast(float, __builtin_amdgcn_update_dpp(__builtin_bit_cast(int, v), __builtin_bit_cast(int, v), 0x118, 0xF, 0xF, false)); v = fmaxf(v, t); // row_shr:8
  t = __builtin_bit_cast(float, __builtin_amdgcn_update_dpp(__builtin_bit_cast(int, v), __builtin_bit_cast(int, v), 0x142, 0xF, 0xF, false)); v = fmaxf(v, t); // row_bcast:15
  t = __builtin_bit_cast(float, __builtin_amdgcn_update_dpp(__builtin_bit_cast(int, v), __builtin_bit_cast(int, v), 0x143, 0xF, 0xF, false)); v = fmaxf(v, t); // row_bcast:31
  return __builtin_bit_cast(float, __builtin_amdgcn_readlane(__builtin_bit_cast(int, v), 63));
}

// ---------------- fused prep + x copy + Wt bf16 cast (UNCHANGED R8) ----------------
__global__ __launch_bounds__(256) void k_pre(const float4* __restrict__ x4,
                                             const float* __restrict__ affines,
                                             const int* __restrict__ prot_mask,
                                             const float* __restrict__ lit,
                                             const float* __restrict__ w,
                                             float* __restrict__ out,
                                             float4* __restrict__ pos4,
                                             float4* __restrict__ ncac4,
                                             unsigned short* __restrict__ wtb) {
  int t = blockIdx.x * 256 + threadIdx.x;  // < 655360
  if (t < 524288) {  // copy x into x_ne rows (embedding cols written by gemm)
    int n = t >> 6, c = t & 63;
    ((float4*)out)[n * 80 + c] = x4[t];
  } else {  // bf16 cast of ne_weight -> wtb[64][2048] (K-contiguous, zero pad)
    int u = t - 524288;  // < 131072
    int o = u >> 11, k = u & 2047;
    wtb[u] = (k < 2000) ? f2bf(w[(size_t)o * 2000 + k]) : (unsigned short)0;
  }
  if (t < NNODES) {  // prep: positions, n2, ncac
    int n = t;
    const float4* af = (const float4*)affines + (size_t)n * 3;
    float4 a0 = af[0], a1 = af[1], a2 = af[2];  // rows of rot, .w = trans
    float tx = a0.w, ty = a1.w, tz = a2.w;
    float n2;
    {
#pragma clang fp contract(off)
      // np: sum(pos*pos,-1) = ((x*x + y*y) + z*z), each op rounded, NO fma
      float xx = tx * tx;
      float yy = ty * ty;
      float zz = tz * tz;
      n2 = (xx + yy) + zz;
    }
    pos4[n] = make_float4(tx, ty, tz, n2);
    out[O_POS + n * 3 + 0] = tx;
    out[O_POS + n * 3 + 1] = ty;
    out[O_POS + n * 3 + 2] = tz;
    int aat = (prot_mask[n] != 0) ? 0 : 20;
    const float* lp = lit + aat * 9;
#pragma unroll
    for (int a = 0; a < 3; a++) {
      float l0 = lp[a * 3 + 0], l1 = lp[a * 3 + 1], l2 = lp[a * 3 + 2];
      // ncac[a][i] = sum_j rot[i][j]*lit[a][j] + trans[i]
      float x = a0.x * l0 + a0.y * l1 + a0.z * l2 + tx;
      float y = a1.x * l0 + a1.y * l1 + a1.z * l2 + ty;
      float z = a2.x * l0 + a2.y * l1 + a2.z * l2 + tz;
      ncac4[n * 3 + a] = make_float4(x, y, z, 0.f);
    }
  }
}

// ---------------- fused KNN + gather: Q=4 queries/block, two-pass ----------------
// d2 arithmetic bit-identical to all passing rounds:
//   dot = fmaf(z_i,z_j, fmaf(y_i,y_j, x_i*x_j)); d2 = (n2_i+n2_j) - 2*dot
// Pass 1: per-thread running min per query (queries in SGPRs; no d2 storage).
// Pivot(q) = 21st-smallest of 64 partition minima (partitions of 128 cands;
// self not excluded in scan, hence 21 => >=20 non-self elements <= pivot).
// Pass 2: recompute d2 (identical expr), survivors (d2<=pivot && c!=q) pushed
// via LDS atomics; exact u64 (key<<13|idx) rank-select -> top-20 (same tie
// semantics as R6-R10: ascending (d2,idx)).
__global__ __launch_bounds__(256) void k_knng(const float4* __restrict__ pos4,
                                              const float* __restrict__ affines,
                                              const float4* __restrict__ ncac4,
                                              float* __restrict__ out,
                                              unsigned short* __restrict__ enc) {
  __shared__ float minb[QB][256];              // per-thread minima (4 KB)
  __shared__ float mca[QB][64];                // 128-cand partition minima
  __shared__ float pivots[QB];
  __shared__ unsigned int cnt[QB];
  __shared__ unsigned long long surv[QB][SCAP];  // 6 KB
  __shared__ int nidx[QB][KZ];
  __shared__ float distbuf[QB][100];
  int tid = threadIdx.x;
  int lane = tid & 63, w = tid >> 6;
  int qbase = blockIdx.x * QB;
  // query positions: wave-uniform -> scalar regs
  float4 q0 = pos4[qbase + 0], q1 = pos4[qbase + 1];
  float4 q2 = pos4[qbase + 2], q3 = pos4[qbase + 3];
  const float4* pp = pos4 + tid;
  float l0 = __builtin_inff(), l1 = l0, l2 = l0, l3 = l0;
  {  // ---- pass 1: minima only ----
#pragma clang fp contract(off)
#pragma unroll
    for (int s = 0; s < 32; s++) {
      float4 pc = pp[s << 8];
      float d0 = (q0.w + pc.w) - 2.0f * fmaf(q0.z, pc.z, fmaf(q0.y, pc.y, q0.x * pc.x));
      float d1 = (q1.w + pc.w) - 2.0f * fmaf(q1.z, pc.z, fmaf(q1.y, pc.y, q1.x * pc.x));
      float d2 = (q2.w + pc.w) - 2.0f * fmaf(q2.z, pc.z, fmaf(q2.y, pc.y, q2.x * pc.x));
      float d3 = (q3.w + pc.w) - 2.0f * fmaf(q3.z, pc.z, fmaf(q3.y, pc.y, q3.x * pc.x));
      l0 = fminf(l0, d0); l1 = fminf(l1, d1);
      l2 = fminf(l2, d2); l3 = fminf(l3, d3);
    }
  }
  minb[0][tid] = l0; minb[1][tid] = l1; minb[2][tid] = l2; minb[3][tid] = l3;
  __syncthreads();
  {  // ---- pivot: wave w handles query w ----
    float m = fminf(fminf(minb[w][lane], minb[w][lane + 64]),
                    fminf(minb[w][lane + 128], minb[w][lane + 192]));
    mca[w][lane] = m;
    __builtin_amdgcn_s_waitcnt(0);
    __builtin_amdgcn_wave_barrier();
    int c = 0;
#pragma unroll 8
    for (int j = 0; j < 64; j++) c += (mca[w][j] < m) ? 1 : 0;
    float elig = (c < KZ + 1) ? m : -__builtin_inff();
    float piv = wave_max_f32(elig);
    if (lane == 0) { pivots[w] = piv; cnt[w] = 0u; }
  }
  __syncthreads();
  float p0 = pivots[0], p1 = pivots[1], p2 = pivots[2], p3 = pivots[3];
  {  // ---- pass 2: recompute + compact survivors ----
#pragma clang fp contract(off)
#pragma unroll 8
    for (int s = 0; s < 32; s++) {
      float4 pc = pp[s << 8];
      float d0 = (q0.w + pc.w) - 2.0f * fmaf(q0.z, pc.z, fmaf(q0.y, pc.y, q0.x * pc.x));
      float d1 = (q1.w + pc.w) - 2.0f * fmaf(q1.z, pc.z, fmaf(q1.y, pc.y, q1.x * pc.x));
      float d2 = (q2.w + pc.w) - 2.0f * fmaf(q2.z, pc.z, fmaf(q2.y, pc.y, q2.x * pc.x));
      float d3 = (q3.w + pc.w) - 2.0f * fmaf(q3.z, pc.z, fmaf(q3.y, pc.y, q3.x * pc.x));
      int cc = (s << 8) + tid;
      float dv[QB] = {d0, d1, d2, d3};
#pragma unroll
      for (int q = 0; q < QB; q++) {
        float pv = (q == 0) ? p0 : (q == 1) ? p1 : (q == 2) ? p2 : p3;
        if (dv[q] <= pv && cc != qbase + q) {
          unsigned int b = __float_as_uint(dv[q]);
          unsigned int k = (b & 0x80000000u) ? ~b : (b | 0x80000000u);
          unsigned int ix = atomicAdd(&cnt[q], 1u);
          if (ix < SCAP)  // guard (never hit for this data)
            surv[q][ix] = ((unsigned long long)k << 13) | (unsigned int)cc;
        }
      }
    }
  }
  __syncthreads();
  {  // ---- exact rank-select: wave w handles query w ----
    unsigned int n = cnt[w]; if (n > SCAP) n = SCAP;
    int qi = qbase + w;
    for (unsigned int j = lane; j < n; j += 64) {
      unsigned long long my = surv[w][j];
      int rank = 0;
      for (unsigned int t = 0; t < n; t++) rank += (surv[w][t] < my) ? 1 : 0;
      if (rank < KZ) {
        int idx = (int)(my & 0x1FFFull);
        nidx[w][rank] = idx;
        float fi = (float)idx;
        out[O_EDGE + qi * KZ + rank] = fi;                   // edge_index
        out[O_FE + qi * KZ + rank] = fi;                     // full_edge row0
        out[O_FE + NNODES * KZ + qi * KZ + rank] = (float)qi;  // full_edge row1
      }
    }
  }
  __syncthreads();
  // ---- gather tail: wave w serves query w, lanes 0..19 ----
  int qi = qbase + w;
  if (lane < KZ) {
    const float4* af = (const float4*)affines + (size_t)qi * 3;
    float4 a0 = af[0], a1 = af[1], a2 = af[2];
    float tx = a0.w, ty = a1.w, tz = a2.w;
    int idx = nidx[w][lane];
    float4 p = pos4[idx];
    float bx = p.x - tx, by = p.y - ty, bz = p.z - tz;
    // einsum('nji,nkj->nki'): v_i = sum_j rot[j][i]*b_j (rot^T; NOT orthogonal)
    float vx = a0.x * bx + a1.x * by + a2.x * bz;
    float vy = a0.y * bx + a1.y * by + a2.y * bz;
    float vz = a0.z * bx + a1.z * by + a2.z * bz;
    out[O_NBP + qi * 60 + lane * 3 + 0] = vx;
    out[O_NBP + qi * 60 + lane * 3 + 1] = vy;
    out[O_NBP + qi * 60 + lane * 3 + 2] = vz;
    float dn = sqrtf(vx * vx + vy * vy + vz * vz);
#pragma unroll
    for (int j = 0; j < 10; j++) {
      float a = dn * FREQS[j];
      out[O_NBD + qi * 400 + lane * 20 + j] = __sinf(a);
      out[O_NBD + qi * 400 + lane * 20 + 10 + j] = __cosf(a);
    }
    float4 cn = ncac4[(size_t)qi * 3 + 0];   // n_pos
    float4 ca = ncac4[(size_t)qi * 3 + 1];   // ca_pos
    float4 cc = ncac4[(size_t)qi * 3 + 2];   // c_pos
    float4 nb0 = ncac4[(size_t)idx * 3 + 0];
    float4 nb1 = ncac4[(size_t)idx * 3 + 1];
    float4 nb2 = ncac4[(size_t)idx * 3 + 2];
    auto dist = [](float4 a, float4 b) {
      float dx = a.x - b.x, dy = a.y - b.y, dz = a.z - b.z;
      return sqrtf(dx * dx + dy * dy + dz * dz);
    };
    distbuf[w][lane * 3 + 0] = dist(nb0, ca);
    distbuf[w][lane * 3 + 1] = dist(nb1, ca);
    distbuf[w][lane * 3 + 2] = dist(nb2, ca);
    distbuf[w][60 + lane] = dist(nb2, cn);  // n_to_c
    distbuf[w][80 + lane] = dist(nb0, cc);  // c_to_n
  }
  __syncthreads();
  // ---- enc encode (bf16): 4 rows x 100 cols over 256 threads ----
  for (int u = tid; u < QB * 100; u += 256) {
    int q = u / 100, col = u - q * 100;
    float d = distbuf[q][col];
    unsigned short sh[20];
#pragma unroll
    for (int j = 0; j < 10; j++) {
      float a = d * FREQS[j];
      sh[j] = f2bf(__sinf(a));
      sh[10 + j] = f2bf(__cosf(a));
    }
    unsigned int* dst = (unsigned int*)(enc + (size_t)(qbase + q) * 2048 + col * 20);
#pragma unroll
    for (int wq = 0; wq < 10; wq++)
      dst[wq] = (unsigned int)sh[2 * wq] | ((unsigned int)sh[2 * wq + 1] << 16);
  }
  if (tid < QB * 24) {  // zero K-pad [2000,2048) per row
    int q = tid / 24, wd = tid - q * 24;
    ((unsigned int*)(enc + (size_t)(qbase + q) * 2048 + 2000))[wd] = 0u;
  }
}

// ---------------- MFMA GEMM (UNCHANGED R8) ----------------
__global__ __launch_bounds__(256) void k_gemm(const unsigned short* __restrict__ enc,
                                              const unsigned short* __restrict__ wtb,
                                              float* __restrict__ out) {
  __shared__ float red[4][16][68];  // +4 pad: conflict-free, 16B-aligned rows
  int tid = threadIdx.x;
  int w = tid >> 6, lane = tid & 63;
  int m0 = blockIdx.x * 16;
  int am = lane & 15, ak = (lane >> 4) * 8;
  const unsigned short* arow = enc + (size_t)(m0 + am) * 2048 + w * 512 + ak;
  const unsigned short* brow = wtb + (size_t)am * 2048 + w * 512 + ak;
  f32x4 acc0 = {0.f, 0.f, 0.f, 0.f}, acc1 = acc0, acc2 = acc0, acc3 = acc0;
#pragma unroll 4
  for (int ks = 0; ks < 16; ks++) {
    bfrag a = *(const bfrag*)(arow + ks * 32);
    bfrag b0 = *(const bfrag*)(brow + ks * 32);
    bfrag b1 = *(const bfrag*)(brow + 16 * 2048 + ks * 32);
    bfrag b2 = *(const bfrag*)(brow + 32 * 2048 + ks * 32);
    bfrag b3 = *(const bfrag*)(brow + 48 * 2048 + ks * 32);
    acc0 = __builtin_amdgcn_mfma_f32_16x16x32_bf16(a, b0, acc0, 0, 0, 0);
    acc1 = __builtin_amdgcn_mfma_f32_16x16x32_bf16(a, b1, acc1, 0, 0, 0);
    acc2 = __builtin_amdgcn_mfma_f32_16x16x32_bf16(a, b2, acc2, 0, 0, 0);
    acc3 = __builtin_amdgcn_mfma_f32_16x16x32_bf16(a, b3, acc3, 0, 0, 0);
  }
  {  // write partials: row=(lane>>4)*4+r, col=lane&15 (+16 per nt)
    int rm = (lane >> 4) * 4, cn = lane & 15;
#pragma unroll
    for (int r = 0; r < 4; r++) {
      red[w][rm + r][cn +  0] = acc0[r];
      red[w][rm + r][cn + 16] = acc1[r];
      red[w][rm + r][cn + 32] = acc2[r];
      red[w][rm + r][cn + 48] = acc3[r];
    }
  }
  __syncthreads();
  // reduce 4 partials; 256 threads x one float4 = 16 rows x 64 cols
  int m = tid >> 4, n = (tid & 15) * 4;
  float4 s0 = *(const float4*)&red[0][m][n];
  float4 s1 = *(const float4*)&red[1][m][n];
  float4 s2 = *(const float4*)&red[2][m][n];
  float4 s3 = *(const float4*)&red[3][m][n];
  float4 s = make_float4(s0.x + s1.x + s2.x + s3.x, s0.y + s1.y + s2.y + s3.y,
                         s0.z + s1.z + s2.z + s3.z, s0.w + s1.w + s2.w + s3.w);
  *(float4*)&out[(size_t)(m0 + m) * 320 + 256 + n] = s;
}

extern "C" void kernel_launch(void* const* d_in, const int* in_sizes, int n_in,
                              void* d_out, int out_size, void* d_ws, size_t ws_size,
                              hipStream_t stream) {
  const float* x = (const float*)d_in[0];
  const float* affines = (const float*)d_in[1];
  const float* ne_w = (const float*)d_in[2];
  const float* lit = (const float*)d_in[3];
  const int* mask = (const int*)d_in[4];
  float* out = (float*)d_out;
  char* ws = (char*)d_ws;
  // ws layout (bytes)
  float4* pos4 = (float4*)(ws + 0);                   //  8192*16   = 131072
  float4* ncac4 = (float4*)(ws + 131072);             //  8192*48   -> 524288
  unsigned short* wtb = (unsigned short*)(ws + 524288);   // 64*2048*2 -> 786432
  unsigned short* enc = (unsigned short*)(ws + 1703936);  // 8192*2048*2 -> 35258368

  k_pre<<<2560, 256, 0, stream>>>((const float4*)x, affines, mask, lit, ne_w,
                                  out, pos4, ncac4, wtb);
  k_knng<<<NNODES / QB, 256, 0, stream>>>(pos4, affines, ncac4, out, enc);
  k_gemm<<<512, 256, 0, stream>>>(enc, wtb, out);
}